// Round 1
// baseline (83.349 us; speedup 1.0000x reference)
//
#include <hip/hip_runtime.h>

#define LOG2E 1.4426950408889634f

__device__ __forceinline__ float rcp_(float x){ return __builtin_amdgcn_rcpf(x); }
__device__ __forceinline__ float ex2_(float x){ return __builtin_amdgcn_exp2f(x); }

// ws layout (floats)
#define WS_A1P  0      // A1 * log2e
#define WS_A2P  1      // A2 * log2e
#define WS_QS   2      // 16: (p1_w @ w) * 2*log2e
#define WS_PB2  18     // 16: p1_b * 2*log2e
#define WS_E1S  34     // 64: exp(m1_w) * 2*log2e
#define WS_M1B2 98     // 64: m1_b * 2*log2e
#define WS_E2S  162    // 4096: exp(m2_w) * 2*log2e   [h][g]
#define WS_M2B2 4258   // 64: m2_b * 2*log2e
#define WS_E3T  4322   // 2048: exp(m3_w) transposed [h][d]
#define WS_TOTAL 6370

__global__ void IDSSM_precompute(const float* __restrict__ Wg,
                                 const float* __restrict__ ag,
                                 const float* __restrict__ p1w,
                                 const float* __restrict__ p1b,
                                 const float* __restrict__ m1w,
                                 const float* __restrict__ m1b,
                                 const float* __restrict__ m2w,
                                 const float* __restrict__ m2b,
                                 const float* __restrict__ m3w,
                                 float* __restrict__ ws)
{
  const int t = threadIdx.x; // 256 threads, 1 block
  if (t == 0){
    float A1 = 0.f, A2 = 0.f;
    for (int d = 0; d < 32; ++d){ A1 += Wg[d]*ag[d]; A2 += Wg[d]*ag[32+d]; }
    ws[WS_A1P] = A1 * LOG2E;
    ws[WS_A2P] = A2 * LOG2E;
  }
  if (t < 16){
    float q = 0.f;
    for (int d = 0; d < 32; ++d) q += p1w[t*32 + d] * Wg[d];
    ws[WS_QS  + t] = q * (2.f * LOG2E);
    ws[WS_PB2 + t] = p1b[t] * (2.f * LOG2E);
  }
  if (t < 64){
    ws[WS_E1S  + t] = expf(m1w[t]) * (2.f * LOG2E);
    ws[WS_M1B2 + t] = m1b[t] * (2.f * LOG2E);
    ws[WS_M2B2 + t] = m2b[t] * (2.f * LOG2E);
  }
  #pragma unroll 1
  for (int r = 0; r < 16; ++r){
    int idx = t*16 + r;
    ws[WS_E2S + idx] = expf(m2w[idx]) * (2.f * LOG2E);
  }
  #pragma unroll 1
  for (int r = 0; r < 8; ++r){
    int idx = t*8 + r;          // idx over m3w flat = d*64 + h
    int d = idx >> 6, h = idx & 63;
    ws[WS_E3T + h*32 + d] = expf(m3w[idx]);
  }
}

__global__ __launch_bounds__(256) void IDSSM_fused(
    const float* __restrict__ xs, const float* __restrict__ stx,
    const float* __restrict__ Wg, const float* __restrict__ p2w,
    const float* __restrict__ p2b, const float* __restrict__ m3b,
    const float* __restrict__ ws, float* __restrict__ out, int B)
{
  __shared__ float lds[256 * 33];   // per-thread padded slot: stride 33 -> conflict-free
  const int tid = threadIdx.x;
  const int b = blockIdx.x * 256 + tid;
  if (b >= B) return;               // no __syncthreads used anywhere
  float* myl = &lds[tid * 33];

  const float A1p = ws[WS_A1P];
  const float A2p = ws[WS_A2P];

  // ---- load x row: LDS copy (dynamic j access) + pre-scaled si[] in regs ----
  float si[32];
  const float4* xr = (const float4*)(xs + (size_t)b * 32);
  #pragma unroll
  for (int q4 = 0; q4 < 8; ++q4){
    float4 v = xr[q4];
    myl[q4*4+0] = v.x; myl[q4*4+1] = v.y; myl[q4*4+2] = v.z; myl[q4*4+3] = v.w;
    si[q4*4+0] = A1p*v.x; si[q4*4+1] = A1p*v.y; si[q4*4+2] = A1p*v.z; si[q4*4+3] = A1p*v.w;
  }

  // ---- attention softmax: for all i at once, loop j ----
  float s[32], sxa[32];
  #pragma unroll
  for (int i = 0; i < 32; ++i){ s[i] = 0.f; sxa[i] = 0.f; }

  float xj = myl[0];
  #pragma unroll 1
  for (int j = 0; j < 32; ++j){
    float xjn = myl[j + 1];         // slot 32 is the pad; value unused on last iter
    float tj = A2p * xj;
    #pragma unroll
    for (int i = 0; i < 32; ++i){
      float v = si[i] + tj;
      float l = fmaxf(v, 0.2f * v); // leaky_relu (already *log2e)
      float p = ex2_(l);
      s[i] += p;
      sxa[i] = fmaf(p, xj, sxa[i]);
    }
    xj = xjn;
  }

  // c_i = weighted mean; park in LDS for dynamic-i second phase
  #pragma unroll
  for (int i = 0; i < 32; ++i) myl[i] = sxa[i] * rcp_(s[i]);

  // ---- pooling: u_i = sum_k p2w_k * tanh(c_i*q_k + p1b_k); beta softmax; Z ----
  float Zs = 0.f, Zd = 0.f;
  const float p2b0 = p2b[0];
  #pragma unroll 1
  for (int i = 0; i < 32; ++i){
    float c = myl[i];
    float u = p2b0;
    #pragma unroll
    for (int k = 0; k < 16; ++k){
      float E  = ex2_(fmaf(c, ws[WS_QS + k], ws[WS_PB2 + k]));
      float th = fmaf(-2.f, rcp_(E + 1.f), 1.f);   // tanh
      u = fmaf(p2w[k], th, u);
    }
    float eb = ex2_(u * LOG2E);
    Zs = fmaf(eb, c, Zs);
    Zd += eb;
  }
  const float Z = Zs * rcp_(Zd);

  {
    float* o = out + (size_t)b * 32;
    #pragma unroll
    for (int d = 0; d < 32; d += 4){
      float4 v = make_float4(Z*Wg[d], Z*Wg[d+1], Z*Wg[d+2], Z*Wg[d+3]);
      *(float4*)(o + d) = v;
    }
  }

  // ---- decoder ----
  const float sx0 = stx[b];
  float h1[64];
  #pragma unroll
  for (int g = 0; g < 64; ++g){
    float E = ex2_(fmaf(sx0, ws[WS_E1S + g], ws[WS_M1B2 + g]));
    h1[g] = fmaf(-2.f, rcp_(E + 1.f), 1.f);
  }
  float zacc[32];
  #pragma unroll
  for (int d = 0; d < 32; ++d) zacc[d] = m3b[d];

  #pragma unroll 1
  for (int h = 0; h < 64; ++h){
    const float* e2 = ws + WS_E2S + h*64;
    float a0 = 0.f, a1 = 0.f, a2 = 0.f, a3 = 0.f;
    #pragma unroll
    for (int g = 0; g < 64; g += 4){
      a0 = fmaf(h1[g+0], e2[g+0], a0);
      a1 = fmaf(h1[g+1], e2[g+1], a1);
      a2 = fmaf(h1[g+2], e2[g+2], a2);
      a3 = fmaf(h1[g+3], e2[g+3], a3);
    }
    float acc = ((a0 + a1) + (a2 + a3)) + ws[WS_M2B2 + h];
    float E  = ex2_(acc);
    float h2 = fmaf(-2.f, rcp_(E + 1.f), 1.f);
    const float* e3 = ws + WS_E3T + h*32;
    #pragma unroll
    for (int d = 0; d < 32; ++d) zacc[d] = fmaf(h2, e3[d], zacc[d]);
  }
  {
    float* o = out + (size_t)B * 32 + (size_t)b * 32;
    #pragma unroll
    for (int d = 0; d < 32; d += 4){
      *(float4*)(o + d) = make_float4(zacc[d], zacc[d+1], zacc[d+2], zacc[d+3]);
    }
  }
}

extern "C" void kernel_launch(void* const* d_in, const int* in_sizes, int n_in,
                              void* d_out, int out_size, void* d_ws, size_t ws_size,
                              hipStream_t stream)
{
  const float* xs  = (const float*)d_in[0];
  const float* stx = (const float*)d_in[1];
  const float* Wg  = (const float*)d_in[2];
  const float* ag  = (const float*)d_in[3];
  const float* p1w = (const float*)d_in[4];
  const float* p1b = (const float*)d_in[5];
  const float* p2w = (const float*)d_in[6];
  const float* p2b = (const float*)d_in[7];
  const float* m1w = (const float*)d_in[8];
  const float* m1b = (const float*)d_in[9];
  const float* m2w = (const float*)d_in[10];
  const float* m2b = (const float*)d_in[11];
  const float* m3w = (const float*)d_in[12];
  const float* m3b = (const float*)d_in[13];
  float* out = (float*)d_out;
  float* ws  = (float*)d_ws;
  const int B = in_sizes[0] / 32;

  hipLaunchKernelGGL(IDSSM_precompute, dim3(1), dim3(256), 0, stream,
                     Wg, ag, p1w, p1b, m1w, m1b, m2w, m2b, m3w, ws);
  const int nblk = (B + 255) / 256;
  hipLaunchKernelGGL(IDSSM_fused, dim3(nblk), dim3(256), 0, stream,
                     xs, stx, Wg, p2w, p2b, m3b, ws, out, B);
}

// Round 2
// 47.666 us; speedup vs baseline: 1.7486x; 1.7486x over previous
//
#include <hip/hip_runtime.h>

#define LOG2E     1.4426950408889634f
#define TWO_LOG2E 2.8853900817779268f

__device__ __forceinline__ float rcp_(float x){ return __builtin_amdgcn_rcpf(x); }
__device__ __forceinline__ float ex2_(float x){ return __builtin_amdgcn_exp2f(x); }

// LDS layout (floats)
//   e2s : [64][64]  @ 0      exp(m2_w)*2log2e, row h, col g   (16 KB)
//   e3t : [64][32]  @ 4096   exp(m3_w)^T, row h, col d        (8 KB)
//   xsh : [64][33]  @ 6144   x rows, padded stride 33         (8.45 KB)
//   e1s : 64        @ 8256   exp(m1_w)*2log2e
//   m1b2: 64        @ 8320   m1_b*2log2e
//   m2b2: 64        @ 8384   m2_b*2log2e
//   qsh : 16        @ 8448   (p1_w @ W_gat)*2log2e
//   pb2 : 16        @ 8464   p1_b*2log2e
//   scal: 2         @ 8480   A1*log2e, A2*log2e
#define LDS_FLOATS 8482

#define DOT16(ROW4, HARR, GB) \
  { const float4* rp_ = (ROW4) + ((GB) >> 2); \
    _Pragma("unroll") \
    for (int s4_ = 0; s4_ < 4; ++s4_){ \
      float4 e_ = rp_[s4_]; \
      acc = fmaf(HARR[s4_*4+0], e_.x, acc); \
      acc = fmaf(HARR[s4_*4+1], e_.y, acc); \
      acc = fmaf(HARR[s4_*4+2], e_.z, acc); \
      acc = fmaf(HARR[s4_*4+3], e_.w, acc); \
    } }

#define ZACC_BLK(H2ARR, HBASE) \
  { _Pragma("unroll") \
    for (int t_ = 0; t_ < 16; ++t_){ \
      const float4* r3_ = (const float4*)(e3t + ((HBASE) + t_)*32 + q*8); \
      float4 ea_ = r3_[0], eb_ = r3_[1]; \
      float hv_ = H2ARR[t_]; \
      za[0] = fmaf(hv_, ea_.x, za[0]); za[1] = fmaf(hv_, ea_.y, za[1]); \
      za[2] = fmaf(hv_, ea_.z, za[2]); za[3] = fmaf(hv_, ea_.w, za[3]); \
      za[4] = fmaf(hv_, eb_.x, za[4]); za[5] = fmaf(hv_, eb_.y, za[5]); \
      za[6] = fmaf(hv_, eb_.z, za[6]); za[7] = fmaf(hv_, eb_.w, za[7]); \
    } }

__global__ __launch_bounds__(256, 4) void IDSSM_fused(
    const float* __restrict__ xs,  const float* __restrict__ stx,
    const float* __restrict__ Wg,  const float* __restrict__ ag,
    const float* __restrict__ p1w, const float* __restrict__ p1b,
    const float* __restrict__ p2w, const float* __restrict__ p2b,
    const float* __restrict__ m1w, const float* __restrict__ m1b,
    const float* __restrict__ m2w, const float* __restrict__ m2b,
    const float* __restrict__ m3w, const float* __restrict__ m3b,
    float* __restrict__ out, int B)
{
  __shared__ float lds[LDS_FLOATS];
  float* e2s  = lds;
  float* e3t  = lds + 4096;
  float* xsh  = lds + 6144;
  float* e1s  = lds + 8256;
  float* m1b2 = lds + 8320;
  float* m2b2 = lds + 8384;
  float* qsh  = lds + 8448;
  float* pb2  = lds + 8464;
  float* scal = lds + 8480;

  const int tid = threadIdx.x;
  const int lb  = tid >> 2;      // local b (0..63)
  const int q   = tid & 3;       // quarter (0..3)
  const int b0  = blockIdx.x * 64;
  const int b   = b0 + lb;
  const bool valid = (b < B);

  // ---------------- staging + folded precompute ----------------
  { // e2 = exp(m2_w)*2log2e, linear [h][g]; thread stages 16 floats
    const float4* src = ((const float4*)m2w) + tid*4;
    float4* dst = ((float4*)e2s) + tid*4;
    #pragma unroll
    for (int s = 0; s < 4; ++s){
      float4 v = src[s];
      dst[s] = make_float4(__expf(v.x)*TWO_LOG2E, __expf(v.y)*TWO_LOG2E,
                           __expf(v.z)*TWO_LOG2E, __expf(v.w)*TWO_LOG2E);
    }
  }
  if (tid < 128){ // e3t[h][d] = exp(m3w[d][h])  (m3w flat = d*64+h)
    const int d  = tid >> 2;
    const int hb = (tid & 3) * 16;
    const float4* src = ((const float4*)m3w) + tid*4;
    #pragma unroll
    for (int s = 0; s < 4; ++s){
      float4 v = src[s];
      const int h = hb + s*4;
      e3t[(h+0)*32 + d] = __expf(v.x);
      e3t[(h+1)*32 + d] = __expf(v.y);
      e3t[(h+2)*32 + d] = __expf(v.z);
      e3t[(h+3)*32 + d] = __expf(v.w);
    }
  }
  { // x rows into padded LDS
    int rsrc = b0 + (tid >> 2); if (rsrc >= B) rsrc = B - 1;
    const float4* src = (const float4*)(xs + (size_t)rsrc*32) + (tid & 3)*2;
    float4 v0 = src[0], v1 = src[1];
    float* dst = xsh + (tid >> 2)*33 + (tid & 3)*8;
    dst[0]=v0.x; dst[1]=v0.y; dst[2]=v0.z; dst[3]=v0.w;
    dst[4]=v1.x; dst[5]=v1.y; dst[6]=v1.z; dst[7]=v1.w;
  }
  if (tid < 64){
    e1s[tid]  = __expf(m1w[tid]) * TWO_LOG2E;
    m1b2[tid] = m1b[tid] * TWO_LOG2E;
    m2b2[tid] = m2b[tid] * TWO_LOG2E;
  }
  if (tid >= 64 && tid < 80){
    const int k = tid - 64;
    float acc = 0.f;
    #pragma unroll
    for (int d = 0; d < 32; ++d) acc += p1w[k*32 + d] * Wg[d];
    qsh[k] = acc * TWO_LOG2E;
    pb2[k] = p1b[k] * TWO_LOG2E;
  }
  if (tid == 80){
    float A1 = 0.f, A2 = 0.f;
    #pragma unroll
    for (int d = 0; d < 32; ++d){ A1 += Wg[d]*ag[d]; A2 += Wg[d]*ag[32+d]; }
    scal[0] = A1 * LOG2E;
    scal[1] = A2 * LOG2E;
  }
  __syncthreads();

  // ---------------- attention: 8 i-rows per thread ----------------
  const float A1p = scal[0], A2p = scal[1];
  const float* xrow = xsh + lb*33;
  float si[8], s[8], sxa[8];
  #pragma unroll
  for (int t = 0; t < 8; ++t){
    si[t] = A1p * xrow[q*8 + t];
    s[t] = 0.f; sxa[t] = 0.f;
  }
  #pragma unroll 4
  for (int j = 0; j < 32; ++j){
    const float xj = xrow[j];
    const float tj = A2p * xj;
    #pragma unroll
    for (int t = 0; t < 8; ++t){
      float v = si[t] + tj;
      float l = fmaxf(v, 0.2f*v);          // leaky_relu (log2e-scaled domain)
      float p = ex2_(l);
      s[t]  += p;
      sxa[t] = fmaf(p, xj, sxa[t]);
    }
  }

  // ---------------- pooling + beta softmax ----------------
  float Zs = 0.f, Zd = 0.f;
  const float p2b0 = p2b[0];
  #pragma unroll
  for (int t = 0; t < 8; ++t){
    const float c = sxa[t] * rcp_(s[t]);   // c_i
    float u = p2b0;
    #pragma unroll
    for (int k = 0; k < 16; ++k){
      float E  = ex2_(fmaf(c, qsh[k], pb2[k]));
      float th = fmaf(-2.f, rcp_(E + 1.f), 1.f);   // tanh
      u = fmaf(p2w[k], th, u);
    }
    float eb = ex2_(u * LOG2E);
    Zs = fmaf(eb, c, Zs);
    Zd += eb;
  }
  Zs += __shfl_xor(Zs, 1);  Zd += __shfl_xor(Zd, 1);
  Zs += __shfl_xor(Zs, 2);  Zd += __shfl_xor(Zd, 2);
  const float Z = Zs * rcp_(Zd);

  if (valid){
    const float4 w0 = ((const float4*)Wg)[q*2 + 0];
    const float4 w1 = ((const float4*)Wg)[q*2 + 1];
    float4* o = (float4*)(out + (size_t)b*32 + q*8);
    o[0] = make_float4(Z*w0.x, Z*w0.y, Z*w0.z, Z*w0.w);
    o[1] = make_float4(Z*w1.x, Z*w1.y, Z*w1.z, Z*w1.w);
  }

  // ---------------- decoder ----------------
  const int bc = valid ? b : (B - 1);
  const float sx0 = stx[bc];

  // h1 own 16, then butterfly-share to all 64
  float h1a[16], h1b[16], h1c[16], h1d[16];
  #pragma unroll
  for (int t = 0; t < 16; ++t){
    const int g = q*16 + t;
    float E = ex2_(fmaf(sx0, e1s[g], m1b2[g]));
    h1a[t] = fmaf(-2.f, rcp_(E + 1.f), 1.f);
  }
  #pragma unroll
  for (int t = 0; t < 16; ++t) h1b[t] = __shfl_xor(h1a[t], 1);
  #pragma unroll
  for (int t = 0; t < 16; ++t){
    h1c[t] = __shfl_xor(h1a[t], 2);
    h1d[t] = __shfl_xor(h1b[t], 2);
  }
  const int gb0 = q*16, gb1 = (q^1)*16, gb2 = (q^2)*16, gb3 = (q^3)*16;

  // h2 for own 16 h's
  float h2a[16];
  #pragma unroll
  for (int t = 0; t < 16; ++t){
    const int h = q*16 + t;
    const float4* row4 = (const float4*)(e2s + h*64);
    float acc = m2b2[h];
    DOT16(row4, h1a, gb0);
    DOT16(row4, h1b, gb1);
    DOT16(row4, h1c, gb2);
    DOT16(row4, h1d, gb3);
    float E = ex2_(acc);                   // acc already *2log2e
    h2a[t] = fmaf(-2.f, rcp_(E + 1.f), 1.f);
  }
  // butterfly-share h2 to all 64
  float h2b[16], h2c[16], h2d[16];
  #pragma unroll
  for (int t = 0; t < 16; ++t) h2b[t] = __shfl_xor(h2a[t], 1);
  #pragma unroll
  for (int t = 0; t < 16; ++t){
    h2c[t] = __shfl_xor(h2a[t], 2);
    h2d[t] = __shfl_xor(h2b[t], 2);
  }

  // z_dec: own 8 d's over all 64 h
  float za[8];
  {
    const float4* mb = (const float4*)(m3b + q*8);
    float4 b0v = mb[0], b1v = mb[1];
    za[0]=b0v.x; za[1]=b0v.y; za[2]=b0v.z; za[3]=b0v.w;
    za[4]=b1v.x; za[5]=b1v.y; za[6]=b1v.z; za[7]=b1v.w;
  }
  ZACC_BLK(h2a, q*16);
  ZACC_BLK(h2b, (q^1)*16);
  ZACC_BLK(h2c, (q^2)*16);
  ZACC_BLK(h2d, (q^3)*16);

  if (valid){
    float* o = out + (size_t)B*32 + (size_t)b*32 + q*8;
    ((float4*)o)[0] = make_float4(za[0], za[1], za[2], za[3]);
    ((float4*)o)[1] = make_float4(za[4], za[5], za[6], za[7]);
  }
}

extern "C" void kernel_launch(void* const* d_in, const int* in_sizes, int n_in,
                              void* d_out, int out_size, void* d_ws, size_t ws_size,
                              hipStream_t stream)
{
  const float* xs  = (const float*)d_in[0];
  const float* stx = (const float*)d_in[1];
  const float* Wg  = (const float*)d_in[2];
  const float* ag  = (const float*)d_in[3];
  const float* p1w = (const float*)d_in[4];
  const float* p1b = (const float*)d_in[5];
  const float* p2w = (const float*)d_in[6];
  const float* p2b = (const float*)d_in[7];
  const float* m1w = (const float*)d_in[8];
  const float* m1b = (const float*)d_in[9];
  const float* m2w = (const float*)d_in[10];
  const float* m2b = (const float*)d_in[11];
  const float* m3w = (const float*)d_in[12];
  const float* m3b = (const float*)d_in[13];
  float* out = (float*)d_out;
  const int B = in_sizes[0] / 32;
  const int nblk = (B + 63) / 64;
  hipLaunchKernelGGL(IDSSM_fused, dim3(nblk), dim3(256), 0, stream,
                     xs, stx, Wg, ag, p1w, p1b, p2w, p2b,
                     m1w, m1b, m2w, m2b, m3w, m3b, out, B);
}

// Round 3
// 37.386 us; speedup vs baseline: 2.2294x; 1.2750x over previous
//
#include <hip/hip_runtime.h>
#include <hip/hip_bf16.h>

#define LOG2E     1.4426950408889634f
#define TWO_LOG2E 2.8853900817779268f

typedef __attribute__((ext_vector_type(8))) short bf16x8;
typedef __attribute__((ext_vector_type(4))) float f32x4;

__device__ __forceinline__ float rcp_(float x){ return __builtin_amdgcn_rcpf(x); }
__device__ __forceinline__ float ex2_(float x){ return __builtin_amdgcn_exp2f(x); }

union FragU { bf16x8 v; uint32_t w[4]; };

__device__ __forceinline__ uint16_t f2bf(float x){
  union { __hip_bfloat16 h; uint16_t u; } c; c.h = __float2bfloat16(x); return c.u;
}
__device__ __forceinline__ float bf2f(uint16_t u){
  union { __hip_bfloat16 h; uint16_t u; } c; c.u = u; return __bfloat162float(c.h);
}
// split (a,b) into packed-bf16 hi word and lo (residual) word
__device__ __forceinline__ void split2(float a, float b, uint32_t& whi, uint32_t& wlo){
  uint16_t ah = f2bf(a), bh = f2bf(b);
  uint16_t al = f2bf(a - bf2f(ah)), bl_ = f2bf(b - bf2f(bh));
  whi = (uint32_t)ah | ((uint32_t)bh << 16);
  wlo = (uint32_t)al | ((uint32_t)bl_ << 16);
}
// load 8 contiguous floats, exp(), split into hi/lo frag words
__device__ __forceinline__ void expsplit8(const float* __restrict__ src,
                                          FragU& hi, FragU& lo){
  float4 a = *(const float4*)src;
  float4 b = *(const float4*)(src + 4);
  float e0=__expf(a.x), e1=__expf(a.y), e2=__expf(a.z), e3=__expf(a.w);
  float e4=__expf(b.x), e5=__expf(b.y), e6=__expf(b.z), e7=__expf(b.w);
  split2(e0,e1, hi.w[0], lo.w[0]);
  split2(e2,e3, hi.w[1], lo.w[1]);
  split2(e4,e5, hi.w[2], lo.w[2]);
  split2(e6,e7, hi.w[3], lo.w[3]);
}

__global__ __launch_bounds__(256, 3) void IDSSM_fused(
    const float* __restrict__ xs,  const float* __restrict__ stx,
    const float* __restrict__ Wg,  const float* __restrict__ ag,
    const float* __restrict__ p1w, const float* __restrict__ p1b,
    const float* __restrict__ p2w, const float* __restrict__ p2b,
    const float* __restrict__ m1w, const float* __restrict__ m1b,
    const float* __restrict__ m2w, const float* __restrict__ m2b,
    const float* __restrict__ m3w, const float* __restrict__ m3b,
    float* __restrict__ out, int B)
{
  __shared__ float xsh[64*33];       // x rows, padded stride 33
  __shared__ float e1s2[64];         // exp(m1_w)*2log2e
  __shared__ float m1b2s[64];        // m1_b*2log2e
  __shared__ float qsh[16];          // (p1_w @ W_gat)*2log2e
  __shared__ float pb2[16];          // p1_b*2log2e
  __shared__ float scal[2];          // A1*log2e, A2*log2e

  const int tid = threadIdx.x;
  const int lb  = tid >> 2;          // local b (0..63) for attention phase
  const int q   = tid & 3;           // quarter (0..3)
  const int b0  = blockIdx.x * 64;
  const int b   = b0 + lb;
  const bool valid = (b < B);

  // ---------------- staging ----------------
  { // x rows into padded LDS
    int rsrc = b0 + (tid >> 2); if (rsrc >= B) rsrc = B - 1;
    const float4* src = (const float4*)(xs + (size_t)rsrc*32) + (tid & 3)*2;
    float4 v0 = src[0], v1 = src[1];
    float* dst = xsh + (tid >> 2)*33 + (tid & 3)*8;
    dst[0]=v0.x; dst[1]=v0.y; dst[2]=v0.z; dst[3]=v0.w;
    dst[4]=v1.x; dst[5]=v1.y; dst[6]=v1.z; dst[7]=v1.w;
  }
  if (tid < 64){
    e1s2[tid]  = __expf(m1w[tid]) * TWO_LOG2E;
    m1b2s[tid] = m1b[tid] * TWO_LOG2E;
  }
  if (tid >= 64 && tid < 80){
    const int k = tid - 64;
    float acc = 0.f;
    #pragma unroll
    for (int d = 0; d < 32; ++d) acc += p1w[k*32 + d] * Wg[d];
    qsh[k] = acc * TWO_LOG2E;
    pb2[k] = p1b[k] * TWO_LOG2E;
  }
  if (tid == 80){
    float A1 = 0.f, A2 = 0.f;
    #pragma unroll
    for (int d = 0; d < 32; ++d){ A1 += Wg[d]*ag[d]; A2 += Wg[d]*ag[32+d]; }
    scal[0] = A1 * LOG2E;
    scal[1] = A2 * LOG2E;
  }
  __syncthreads();

  // ---------------- attention: 8 i-rows per thread ----------------
  const float A1p = scal[0], A2p = scal[1];
  const float* xrow = xsh + lb*33;
  float si[8], s[8], sxa[8];
  #pragma unroll
  for (int t = 0; t < 8; ++t){
    si[t] = A1p * xrow[q*8 + t];
    s[t] = 0.f; sxa[t] = 0.f;
  }
  #pragma unroll 4
  for (int j = 0; j < 32; ++j){
    const float xj = xrow[j];
    const float tj = A2p * xj;
    #pragma unroll
    for (int t = 0; t < 8; ++t){
      float v = si[t] + tj;
      float l = fmaxf(v, 0.2f*v);          // leaky_relu (log2e-scaled domain)
      float p = ex2_(l);
      s[t]  += p;
      sxa[t] = fmaf(p, xj, sxa[t]);
    }
  }

  // ---------------- pooling + beta softmax + z_enc ----------------
  float Zs = 0.f, Zd = 0.f;
  const float p2b0 = p2b[0];
  #pragma unroll
  for (int t = 0; t < 8; ++t){
    const float c = sxa[t] * rcp_(s[t]);   // c_i
    float u = p2b0;
    #pragma unroll
    for (int k = 0; k < 16; ++k){
      float E  = ex2_(fmaf(c, qsh[k], pb2[k]));
      float th = fmaf(-2.f, rcp_(E + 1.f), 1.f);   // tanh
      u = fmaf(p2w[k], th, u);
    }
    float eb = ex2_(u * LOG2E);
    Zs = fmaf(eb, c, Zs);
    Zd += eb;
  }
  Zs += __shfl_xor(Zs, 1);  Zd += __shfl_xor(Zd, 1);
  Zs += __shfl_xor(Zs, 2);  Zd += __shfl_xor(Zd, 2);
  const float Z = Zs * rcp_(Zd);

  if (valid){
    const float4 w0 = ((const float4*)Wg)[q*2 + 0];
    const float4 w1 = ((const float4*)Wg)[q*2 + 1];
    float4* o = (float4*)(out + (size_t)b*32 + q*8);
    o[0] = make_float4(Z*w0.x, Z*w0.y, Z*w0.z, Z*w0.w);
    o[1] = make_float4(Z*w1.x, Z*w1.y, Z*w1.z, Z*w1.w);
  }

  // ================= decoder (MFMA) =================
  // Wave handles 16 b's: b = b0 + 16*wv + (lane&15)  (same set as attention).
  const int lane = tid & 63;
  const int wv   = tid >> 6;
  const int gt   = lane >> 4;        // k-slice group (0..3)
  const int bl   = lane & 15;        // b within wave tile
  const int bd   = b0 + wv*16 + bl;
  const float sx0 = stx[(bd < B) ? bd : (B-1)];

  // --- h1 in B-fragment layout: B[k=g][n=b], lane owns b=bl, g=8*gt+j+32*kt
  uint32_t h1hi[2][4], h1lo[2][4];
  #pragma unroll
  for (int kt = 0; kt < 2; ++kt){
    const int g0 = 8*gt + 32*kt;
    float hv[8];
    #pragma unroll
    for (int j = 0; j < 8; ++j){
      float E = ex2_(fmaf(sx0, e1s2[g0+j], m1b2s[g0+j]));
      hv[j] = fmaf(-2.f, rcp_(E + 1.f), 1.f);     // tanh
    }
    #pragma unroll
    for (int jw = 0; jw < 4; ++jw)
      split2(hv[2*jw], hv[2*jw+1], h1hi[kt][jw], h1lo[kt][jw]);
  }

  // --- GEMM1: H2pre^T[h][b] = sum_g exp(m2w[h][g]) * h1[b][g]  (+ m2b[h])
  f32x4 acc[4];
  #pragma unroll
  for (int mt = 0; mt < 4; ++mt){
    float4 bi = *(const float4*)(m2b + 16*mt + 4*gt);
    acc[mt][0]=bi.x; acc[mt][1]=bi.y; acc[mt][2]=bi.z; acc[mt][3]=bi.w;
  }
  #pragma unroll
  for (int mt = 0; mt < 4; ++mt){
    #pragma unroll
    for (int kt = 0; kt < 2; ++kt){
      FragU Ahi, Alo, Bhi, Blo;
      expsplit8(m2w + (bl + 16*mt)*64 + 8*gt + 32*kt, Ahi, Alo);
      Bhi.w[0]=h1hi[kt][0]; Bhi.w[1]=h1hi[kt][1]; Bhi.w[2]=h1hi[kt][2]; Bhi.w[3]=h1hi[kt][3];
      Blo.w[0]=h1lo[kt][0]; Blo.w[1]=h1lo[kt][1]; Blo.w[2]=h1lo[kt][2]; Blo.w[3]=h1lo[kt][3];
      acc[mt] = __builtin_amdgcn_mfma_f32_16x16x32_bf16(Ahi.v, Bhi.v, acc[mt], 0, 0, 0);
      acc[mt] = __builtin_amdgcn_mfma_f32_16x16x32_bf16(Ahi.v, Blo.v, acc[mt], 0, 0, 0);
      acc[mt] = __builtin_amdgcn_mfma_f32_16x16x32_bf16(Alo.v, Bhi.v, acc[mt], 0, 0, 0);
    }
  }

  // --- tanh + pack: lane holds H2^T[h=16mt+4gt+r][b=bl]
  uint32_t Whi[4][2], Wlo[4][2];
  #pragma unroll
  for (int mt = 0; mt < 4; ++mt){
    float t0 = fmaf(-2.f, rcp_(ex2_(acc[mt][0]*TWO_LOG2E) + 1.f), 1.f);
    float t1 = fmaf(-2.f, rcp_(ex2_(acc[mt][1]*TWO_LOG2E) + 1.f), 1.f);
    float t2 = fmaf(-2.f, rcp_(ex2_(acc[mt][2]*TWO_LOG2E) + 1.f), 1.f);
    float t3 = fmaf(-2.f, rcp_(ex2_(acc[mt][3]*TWO_LOG2E) + 1.f), 1.f);
    split2(t0, t1, Whi[mt][0], Wlo[mt][0]);
    split2(t2, t3, Whi[mt][1], Wlo[mt][1]);
  }

  // --- cross-lane transpose into B-fragment layout for GEMM2:
  // dest lane needs h = 8*gt + j + 32*kt2 at b=bl. For word jw (h-pair):
  //   src_lane = bl + 16*(((jw>>1) + 2*gt)&3), src word = W[2*kt2 + (gt>>1)][jw&1]
  FragU B2hi[2], B2lo[2];
  const int hiSel = gt >> 1;
  #pragma unroll
  for (int kt2 = 0; kt2 < 2; ++kt2){
    #pragma unroll
    for (int jw = 0; jw < 4; ++jw){
      const int sl = bl + 16*(((jw>>1) + 2*gt) & 3);
      const int w  = jw & 1;
      uint32_t c0 = (uint32_t)__shfl((int)Whi[2*kt2+0][w], sl);
      uint32_t c1 = (uint32_t)__shfl((int)Whi[2*kt2+1][w], sl);
      B2hi[kt2].w[jw] = hiSel ? c1 : c0;
      uint32_t d0 = (uint32_t)__shfl((int)Wlo[2*kt2+0][w], sl);
      uint32_t d1 = (uint32_t)__shfl((int)Wlo[2*kt2+1][w], sl);
      B2lo[kt2].w[jw] = hiSel ? d1 : d0;
    }
  }

  // --- GEMM2: Z^T[d][b] = sum_h exp(m3w[d][h]) * H2[b][h]  (+ m3b[d])
  f32x4 acc2[2];
  #pragma unroll
  for (int mt2 = 0; mt2 < 2; ++mt2){
    float4 bi = *(const float4*)(m3b + 16*mt2 + 4*gt);
    acc2[mt2][0]=bi.x; acc2[mt2][1]=bi.y; acc2[mt2][2]=bi.z; acc2[mt2][3]=bi.w;
  }
  #pragma unroll
  for (int mt2 = 0; mt2 < 2; ++mt2){
    #pragma unroll
    for (int kt2 = 0; kt2 < 2; ++kt2){
      FragU Ahi, Alo;
      expsplit8(m3w + (bl + 16*mt2)*64 + 8*gt + 32*kt2, Ahi, Alo);
      acc2[mt2] = __builtin_amdgcn_mfma_f32_16x16x32_bf16(Ahi.v, B2hi[kt2].v, acc2[mt2], 0, 0, 0);
      acc2[mt2] = __builtin_amdgcn_mfma_f32_16x16x32_bf16(Ahi.v, B2lo[kt2].v, acc2[mt2], 0, 0, 0);
      acc2[mt2] = __builtin_amdgcn_mfma_f32_16x16x32_bf16(Alo.v, B2hi[kt2].v, acc2[mt2], 0, 0, 0);
    }
  }

  // --- store z_dec: lane holds Z[b=bl][d=16*mt2+4*gt+r] -> contiguous float4
  if (bd < B){
    float* o = out + (size_t)B*32 + (size_t)bd*32;
    *(float4*)(o + 4*gt)      = make_float4(acc2[0][0], acc2[0][1], acc2[0][2], acc2[0][3]);
    *(float4*)(o + 16 + 4*gt) = make_float4(acc2[1][0], acc2[1][1], acc2[1][2], acc2[1][3]);
  }
}

extern "C" void kernel_launch(void* const* d_in, const int* in_sizes, int n_in,
                              void* d_out, int out_size, void* d_ws, size_t ws_size,
                              hipStream_t stream)
{
  const float* xs  = (const float*)d_in[0];
  const float* stx = (const float*)d_in[1];
  const float* Wg  = (const float*)d_in[2];
  const float* ag  = (const float*)d_in[3];
  const float* p1w = (const float*)d_in[4];
  const float* p1b = (const float*)d_in[5];
  const float* p2w = (const float*)d_in[6];
  const float* p2b = (const float*)d_in[7];
  const float* m1w = (const float*)d_in[8];
  const float* m1b = (const float*)d_in[9];
  const float* m2w = (const float*)d_in[10];
  const float* m2b = (const float*)d_in[11];
  const float* m3w = (const float*)d_in[12];
  const float* m3b = (const float*)d_in[13];
  float* out = (float*)d_out;
  const int B = in_sizes[0] / 32;
  const int nblk = (B + 63) / 64;
  hipLaunchKernelGGL(IDSSM_fused, dim3(nblk), dim3(256), 0, stream,
                     xs, stx, Wg, ag, p1w, p1b, p2w, p2b,
                     m1w, m1b, m2w, m2b, m3w, m3b, out, B);
}

// Round 4
// 33.701 us; speedup vs baseline: 2.4732x; 1.1094x over previous
//
#include <hip/hip_runtime.h>
#include <hip/hip_bf16.h>

#define LOG2E     1.4426950408889634f
#define TWO_LOG2E 2.8853900817779268f

typedef __attribute__((ext_vector_type(8))) short bf16x8;
typedef __attribute__((ext_vector_type(4))) float f32x4;

__device__ __forceinline__ float rcp_(float x){ return __builtin_amdgcn_rcpf(x); }
__device__ __forceinline__ float ex2_(float x){ return __builtin_amdgcn_exp2f(x); }

union FragU { bf16x8 v; uint32_t w[4]; uint4 u4; };

__device__ __forceinline__ uint16_t f2bf(float x){
  union { __hip_bfloat16 h; uint16_t u; } c; c.h = __float2bfloat16(x); return c.u;
}
__device__ __forceinline__ float bf2f(uint16_t u){
  union { __hip_bfloat16 h; uint16_t u; } c; c.u = u; return __bfloat162float(c.h);
}
// split (a,b) into packed-bf16 hi word and lo (residual) word
__device__ __forceinline__ void split2(float a, float b, uint32_t& whi, uint32_t& wlo){
  uint16_t ah = f2bf(a), bh = f2bf(b);
  uint16_t al = f2bf(a - bf2f(ah)), bl_ = f2bf(b - bf2f(bh));
  whi = (uint32_t)ah | ((uint32_t)bh << 16);
  wlo = (uint32_t)al | ((uint32_t)bl_ << 16);
}
// load 8 contiguous floats, exp(), split into hi/lo frag words
__device__ __forceinline__ void expsplit8(const float* __restrict__ src,
                                          FragU& hi, FragU& lo){
  float4 a = *(const float4*)src;
  float4 b = *(const float4*)(src + 4);
  float e0=__expf(a.x), e1=__expf(a.y), e2=__expf(a.z), e3=__expf(a.w);
  float e4=__expf(b.x), e5=__expf(b.y), e6=__expf(b.z), e7=__expf(b.w);
  split2(e0,e1, hi.w[0], lo.w[0]);
  split2(e2,e3, hi.w[1], lo.w[1]);
  split2(e4,e5, hi.w[2], lo.w[2]);
  split2(e6,e7, hi.w[3], lo.w[3]);
}

__global__ __launch_bounds__(256, 4) void IDSSM_fused(
    const float* __restrict__ xs,  const float* __restrict__ stx,
    const float* __restrict__ Wg,  const float* __restrict__ ag,
    const float* __restrict__ p1w, const float* __restrict__ p1b,
    const float* __restrict__ p2w, const float* __restrict__ p2b,
    const float* __restrict__ m1w, const float* __restrict__ m1b,
    const float* __restrict__ m2w, const float* __restrict__ m2b,
    const float* __restrict__ m3w, const float* __restrict__ m3b,
    float* __restrict__ out, int B)
{
  __shared__ float xsh[64*33];       // x rows, padded stride 33 (8448 f)
  __shared__ uint4 fghi[12][64];     // weight frags hi: slots 0-7 GEMM1, 8-11 GEMM2
  __shared__ uint4 fglo[12][64];     // weight frags lo
  __shared__ float e1s2[64];         // exp(m1_w)*2log2e
  __shared__ float m1b2s[64];        // m1_b*2log2e
  __shared__ float qsh[16];          // (p1_w @ W_gat)*2log2e
  __shared__ float pbb[16];          // p1_b*2log2e
  __shared__ float p2wn[16];         // -2*p2w
  __shared__ float scal[3];          // A1*log2e, A2*log2e, p2b0+sum(p2w)

  const int tid = threadIdx.x;
  const int lb  = tid >> 2;          // local b (0..63) for attention phase
  const int q   = tid & 3;           // quarter (0..3)
  const int b0  = blockIdx.x * 64;
  const int b   = b0 + lb;
  const bool valid = (b < B);

  // ---------------- staging (once per block, amortized over 4 waves) --------
  { // x rows into padded LDS
    int rsrc = b0 + (tid >> 2); if (rsrc >= B) rsrc = B - 1;
    const float4* src = (const float4*)(xs + (size_t)rsrc*32) + (tid & 3)*2;
    float4 v0 = src[0], v1 = src[1];
    float* dst = xsh + (tid >> 2)*33 + (tid & 3)*8;
    dst[0]=v0.x; dst[1]=v0.y; dst[2]=v0.z; dst[3]=v0.w;
    dst[4]=v1.x; dst[5]=v1.y; dst[6]=v1.z; dst[7]=v1.w;
  }
  // decoder weight fragments: 12 slots x 64 lanes; each thread builds 3 sets.
  // slot<8: GEMM1 A = exp(m2w), slot = mt*2+kt; slot>=8: GEMM2 A = exp(m3w).
  #pragma unroll
  for (int rep = 0; rep < 3; ++rep){
    const int s    = tid + rep*256;
    const int slot = s >> 6;
    const int l    = s & 63;
    const int bl_  = l & 15;
    const int gt_  = l >> 4;
    const float* src;
    if (slot < 8) src = m2w + (bl_ + 16*(slot>>1))*64 + 8*gt_ + 32*(slot&1);
    else { const int s2 = slot - 8;
           src = m3w + (bl_ + 16*(s2>>1))*64 + 8*gt_ + 32*(s2&1); }
    FragU hi, lo;
    expsplit8(src, hi, lo);
    fghi[slot][l] = hi.u4;
    fglo[slot][l] = lo.u4;
  }
  if (tid < 64){
    e1s2[tid]  = __expf(m1w[tid]) * TWO_LOG2E;
    m1b2s[tid] = m1b[tid] * TWO_LOG2E;
  }
  if (tid >= 64 && tid < 80){
    const int k = tid - 64;
    float acc = 0.f;
    #pragma unroll
    for (int d = 0; d < 32; ++d) acc += p1w[k*32 + d] * Wg[d];
    qsh[k]  = acc * TWO_LOG2E;
    pbb[k]  = p1b[k] * TWO_LOG2E;
    p2wn[k] = -2.f * p2w[k];
  }
  if (tid == 80){
    float A1 = 0.f, A2 = 0.f;
    #pragma unroll
    for (int d = 0; d < 32; ++d){ A1 += Wg[d]*ag[d]; A2 += Wg[d]*ag[32+d]; }
    scal[0] = A1 * LOG2E;
    scal[1] = A2 * LOG2E;
  }
  if (tid == 81){
    float sp = 0.f;
    #pragma unroll
    for (int k = 0; k < 16; ++k) sp += p2w[k];
    scal[2] = sp + p2b[0];
  }
  __syncthreads();

  // ---------------- attention: 8 i-rows per thread ----------------
  const float A1p = scal[0], A2p = scal[1];
  const float* xrow = xsh + lb*33;
  float si[8], s[8], sxa[8];
  #pragma unroll
  for (int t = 0; t < 8; ++t){
    si[t] = A1p * xrow[q*8 + t];
    s[t] = 0.f; sxa[t] = 0.f;
  }
  #pragma unroll 4
  for (int j = 0; j < 32; ++j){
    const float xj = xrow[j];
    const float tj = A2p * xj;
    #pragma unroll
    for (int t = 0; t < 8; ++t){
      float v = si[t] + tj;
      float l = fmaxf(v, 0.2f*v);          // leaky_relu (log2e-scaled domain)
      float p = ex2_(l);
      s[t]  += p;
      sxa[t] = fmaf(p, xj, sxa[t]);
    }
  }

  // ---------------- pooling + beta softmax + z_enc ----------------
  // sum_k p2w_k*tanh(.) = sum(p2w) + sum_k (-2 p2w_k)*rcp(E_k+1)
  float Zs = 0.f, Zd = 0.f;
  const float u0 = scal[2];
  #pragma unroll
  for (int t = 0; t < 8; ++t){
    const float c = sxa[t] * rcp_(s[t]);   // c_i
    float u = u0;
    #pragma unroll
    for (int k = 0; k < 16; ++k){
      float E = ex2_(fmaf(c, qsh[k], pbb[k]));
      u = fmaf(p2wn[k], rcp_(E + 1.f), u);
    }
    float eb = ex2_(u * LOG2E);
    Zs = fmaf(eb, c, Zs);
    Zd += eb;
  }
  Zs += __shfl_xor(Zs, 1);  Zd += __shfl_xor(Zd, 1);
  Zs += __shfl_xor(Zs, 2);  Zd += __shfl_xor(Zd, 2);
  const float Z = Zs * rcp_(Zd);

  if (valid){
    const float4 w0 = ((const float4*)Wg)[q*2 + 0];
    const float4 w1 = ((const float4*)Wg)[q*2 + 1];
    float4* o = (float4*)(out + (size_t)b*32 + q*8);
    o[0] = make_float4(Z*w0.x, Z*w0.y, Z*w0.z, Z*w0.w);
    o[1] = make_float4(Z*w1.x, Z*w1.y, Z*w1.z, Z*w1.w);
  }

  // ================= decoder (MFMA) =================
  // Wave handles 16 b's: b = b0 + 16*wv + (lane&15)  (same set as attention).
  const int lane = tid & 63;
  const int wv   = tid >> 6;
  const int gt   = lane >> 4;        // k-slice group (0..3)
  const int bl   = lane & 15;        // b within wave tile
  const int bd   = b0 + wv*16 + bl;
  const float sx0 = stx[(bd < B) ? bd : (B-1)];

  // --- h1 in B-fragment layout: B[k=g][n=b], lane owns b=bl, g=8*gt+j+32*kt
  uint32_t h1hi[2][4], h1lo[2][4];
  #pragma unroll
  for (int kt = 0; kt < 2; ++kt){
    const int g0 = 8*gt + 32*kt;
    float hv[8];
    #pragma unroll
    for (int j = 0; j < 8; ++j){
      float E = ex2_(fmaf(sx0, e1s2[g0+j], m1b2s[g0+j]));
      hv[j] = fmaf(-2.f, rcp_(E + 1.f), 1.f);     // tanh
    }
    #pragma unroll
    for (int jw = 0; jw < 4; ++jw)
      split2(hv[2*jw], hv[2*jw+1], h1hi[kt][jw], h1lo[kt][jw]);
  }

  // --- GEMM1: H2pre^T[h][b] = sum_g exp(m2w[h][g]) * h1[b][g]  (+ m2b[h])
  f32x4 acc[4];
  #pragma unroll
  for (int mt = 0; mt < 4; ++mt){
    float4 bi = *(const float4*)(m2b + 16*mt + 4*gt);
    acc[mt][0]=bi.x; acc[mt][1]=bi.y; acc[mt][2]=bi.z; acc[mt][3]=bi.w;
  }
  #pragma unroll
  for (int mt = 0; mt < 4; ++mt){
    #pragma unroll
    for (int kt = 0; kt < 2; ++kt){
      FragU Ahi, Alo, Bhi, Blo;
      Ahi.u4 = fghi[mt*2+kt][lane];
      Alo.u4 = fglo[mt*2+kt][lane];
      Bhi.w[0]=h1hi[kt][0]; Bhi.w[1]=h1hi[kt][1]; Bhi.w[2]=h1hi[kt][2]; Bhi.w[3]=h1hi[kt][3];
      Blo.w[0]=h1lo[kt][0]; Blo.w[1]=h1lo[kt][1]; Blo.w[2]=h1lo[kt][2]; Blo.w[3]=h1lo[kt][3];
      acc[mt] = __builtin_amdgcn_mfma_f32_16x16x32_bf16(Ahi.v, Bhi.v, acc[mt], 0, 0, 0);
      acc[mt] = __builtin_amdgcn_mfma_f32_16x16x32_bf16(Ahi.v, Blo.v, acc[mt], 0, 0, 0);
      acc[mt] = __builtin_amdgcn_mfma_f32_16x16x32_bf16(Alo.v, Bhi.v, acc[mt], 0, 0, 0);
    }
  }

  // --- tanh + pack: lane holds H2^T[h=16mt+4gt+r][b=bl]
  uint32_t Whi[4][2], Wlo[4][2];
  #pragma unroll
  for (int mt = 0; mt < 4; ++mt){
    float t0 = fmaf(-2.f, rcp_(ex2_(acc[mt][0]*TWO_LOG2E) + 1.f), 1.f);
    float t1 = fmaf(-2.f, rcp_(ex2_(acc[mt][1]*TWO_LOG2E) + 1.f), 1.f);
    float t2 = fmaf(-2.f, rcp_(ex2_(acc[mt][2]*TWO_LOG2E) + 1.f), 1.f);
    float t3 = fmaf(-2.f, rcp_(ex2_(acc[mt][3]*TWO_LOG2E) + 1.f), 1.f);
    split2(t0, t1, Whi[mt][0], Wlo[mt][0]);
    split2(t2, t3, Whi[mt][1], Wlo[mt][1]);
  }

  // --- cross-lane transpose into B-fragment layout for GEMM2:
  // dest lane needs h = 8*gt + j + 32*kt2 at b=bl. For word jw (h-pair):
  //   src_lane = bl + 16*(((jw>>1) + 2*gt)&3), src word = W[2*kt2 + (gt>>1)][jw&1]
  FragU B2hi[2], B2lo[2];
  const int hiSel = gt >> 1;
  #pragma unroll
  for (int kt2 = 0; kt2 < 2; ++kt2){
    #pragma unroll
    for (int jw = 0; jw < 4; ++jw){
      const int sl = bl + 16*(((jw>>1) + 2*gt) & 3);
      const int w  = jw & 1;
      uint32_t c0 = (uint32_t)__shfl((int)Whi[2*kt2+0][w], sl);
      uint32_t c1 = (uint32_t)__shfl((int)Whi[2*kt2+1][w], sl);
      B2hi[kt2].w[jw] = hiSel ? c1 : c0;
      uint32_t d0 = (uint32_t)__shfl((int)Wlo[2*kt2+0][w], sl);
      uint32_t d1 = (uint32_t)__shfl((int)Wlo[2*kt2+1][w], sl);
      B2lo[kt2].w[jw] = hiSel ? d1 : d0;
    }
  }

  // --- GEMM2: Z^T[d][b] = sum_h exp(m3w[d][h]) * H2[b][h]  (+ m3b[d])
  f32x4 acc2[2];
  #pragma unroll
  for (int mt2 = 0; mt2 < 2; ++mt2){
    float4 bi = *(const float4*)(m3b + 16*mt2 + 4*gt);
    acc2[mt2][0]=bi.x; acc2[mt2][1]=bi.y; acc2[mt2][2]=bi.z; acc2[mt2][3]=bi.w;
  }
  #pragma unroll
  for (int mt2 = 0; mt2 < 2; ++mt2){
    #pragma unroll
    for (int kt2 = 0; kt2 < 2; ++kt2){
      FragU Ahi, Alo;
      Ahi.u4 = fghi[8 + mt2*2 + kt2][lane];
      Alo.u4 = fglo[8 + mt2*2 + kt2][lane];
      acc2[mt2] = __builtin_amdgcn_mfma_f32_16x16x32_bf16(Ahi.v, B2hi[kt2].v, acc2[mt2], 0, 0, 0);
      acc2[mt2] = __builtin_amdgcn_mfma_f32_16x16x32_bf16(Ahi.v, B2lo[kt2].v, acc2[mt2], 0, 0, 0);
      acc2[mt2] = __builtin_amdgcn_mfma_f32_16x16x32_bf16(Alo.v, B2hi[kt2].v, acc2[mt2], 0, 0, 0);
    }
  }

  // --- store z_dec: lane holds Z[b=bl][d=16*mt2+4*gt+r] -> contiguous float4
  if (bd < B){
    float* o = out + (size_t)B*32 + (size_t)bd*32;
    *(float4*)(o + 4*gt)      = make_float4(acc2[0][0], acc2[0][1], acc2[0][2], acc2[0][3]);
    *(float4*)(o + 16 + 4*gt) = make_float4(acc2[1][0], acc2[1][1], acc2[1][2], acc2[1][3]);
  }
}

extern "C" void kernel_launch(void* const* d_in, const int* in_sizes, int n_in,
                              void* d_out, int out_size, void* d_ws, size_t ws_size,
                              hipStream_t stream)
{
  const float* xs  = (const float*)d_in[0];
  const float* stx = (const float*)d_in[1];
  const float* Wg  = (const float*)d_in[2];
  const float* ag  = (const float*)d_in[3];
  const float* p1w = (const float*)d_in[4];
  const float* p1b = (const float*)d_in[5];
  const float* p2w = (const float*)d_in[6];
  const float* p2b = (const float*)d_in[7];
  const float* m1w = (const float*)d_in[8];
  const float* m1b = (const float*)d_in[9];
  const float* m2w = (const float*)d_in[10];
  const float* m2b = (const float*)d_in[11];
  const float* m3w = (const float*)d_in[12];
  const float* m3b = (const float*)d_in[13];
  float* out = (float*)d_out;
  const int B = in_sizes[0] / 32;
  const int nblk = (B + 63) / 64;
  hipLaunchKernelGGL(IDSSM_fused, dim3(nblk), dim3(256), 0, stream,
                     xs, stx, Wg, ag, p1w, p1b, p2w, p2b,
                     m1w, m1b, m2w, m2b, m3w, m3b, out, B);
}

// Round 5
// 31.408 us; speedup vs baseline: 2.6537x; 1.0730x over previous
//
#include <hip/hip_runtime.h>
#include <hip/hip_bf16.h>

#define LOG2E     1.4426950408889634f
#define TWO_LOG2E 2.8853900817779268f

typedef __attribute__((ext_vector_type(8))) short bf16x8;
typedef __attribute__((ext_vector_type(4))) float f32x4;
typedef __attribute__((ext_vector_type(2))) float f32x2;

__device__ __forceinline__ float rcp_(float x){ return __builtin_amdgcn_rcpf(x); }
__device__ __forceinline__ float ex2_(float x){ return __builtin_amdgcn_exp2f(x); }

union FragU { bf16x8 v; uint32_t w[4]; uint4 u4; };

__device__ __forceinline__ uint16_t f2bf(float x){
  union { __hip_bfloat16 h; uint16_t u; } c; c.h = __float2bfloat16(x); return c.u;
}
__device__ __forceinline__ float bf2f(uint16_t u){
  union { __hip_bfloat16 h; uint16_t u; } c; c.u = u; return __bfloat162float(c.h);
}
// split (a,b) into packed-bf16 hi word and lo (residual) word
__device__ __forceinline__ void split2(float a, float b, uint32_t& whi, uint32_t& wlo){
  uint16_t ah = f2bf(a), bh = f2bf(b);
  uint16_t al = f2bf(a - bf2f(ah)), bl_ = f2bf(b - bf2f(bh));
  whi = (uint32_t)ah | ((uint32_t)bh << 16);
  wlo = (uint32_t)al | ((uint32_t)bl_ << 16);
}
// load 8 contiguous floats, exp(), split into hi/lo frag words
__device__ __forceinline__ void expsplit8(const float* __restrict__ src,
                                          FragU& hi, FragU& lo){
  float4 a = *(const float4*)src;
  float4 b = *(const float4*)(src + 4);
  float e0=__expf(a.x), e1=__expf(a.y), e2=__expf(a.z), e3=__expf(a.w);
  float e4=__expf(b.x), e5=__expf(b.y), e6=__expf(b.z), e7=__expf(b.w);
  split2(e0,e1, hi.w[0], lo.w[0]);
  split2(e2,e3, hi.w[1], lo.w[1]);
  split2(e4,e5, hi.w[2], lo.w[2]);
  split2(e6,e7, hi.w[3], lo.w[3]);
}

#define TBL_N     1024
#define TBL_SCALE 51.2f          // TBL_N / 20
#define TBL_LO    -10.0f
#define TBL_CMAX  9.97f

__global__ __launch_bounds__(256, 4) void IDSSM_fused(
    const float* __restrict__ xs,  const float* __restrict__ stx,
    const float* __restrict__ Wg,  const float* __restrict__ ag,
    const float* __restrict__ p1w, const float* __restrict__ p1b,
    const float* __restrict__ p2w, const float* __restrict__ p2b,
    const float* __restrict__ m1w, const float* __restrict__ m1b,
    const float* __restrict__ m2w, const float* __restrict__ m2b,
    const float* __restrict__ m3w, const float* __restrict__ m3b,
    float* __restrict__ out, int B)
{
  __shared__ float xsh[64*33];       // x rows, padded stride 33
  __shared__ uint4 fghi[12][64];     // weight frags hi: slots 0-7 GEMM1, 8-11 GEMM2
  __shared__ uint4 fglo[12][64];     // weight frags lo
  __shared__ float tbl[TBL_N];       // u(c)*log2e PWL table
  __shared__ float e1s2[64];         // exp(m1_w)*2log2e
  __shared__ float m1b2s[64];        // m1_b*2log2e
  __shared__ float qsh[16];          // (p1_w @ W_gat)*2log2e
  __shared__ float pbb[16];          // p1_b*2log2e
  __shared__ float p2wn[16];         // -2*p2w
  __shared__ float scal[3];          // A1*log2e, A2*log2e, p2b0+sum(p2w)

  const int tid = threadIdx.x;
  const int lb  = tid >> 2;          // local b (0..63) for attention phase
  const int q   = tid & 3;           // quarter (0..3)
  const int b0  = blockIdx.x * 64;
  const int b   = b0 + lb;
  const bool valid = (b < B);

  // ---------------- staging phase A ----------------
  { // x rows into padded LDS
    int rsrc = b0 + (tid >> 2); if (rsrc >= B) rsrc = B - 1;
    const float4* src = (const float4*)(xs + (size_t)rsrc*32) + (tid & 3)*2;
    float4 v0 = src[0], v1 = src[1];
    float* dst = xsh + (tid >> 2)*33 + (tid & 3)*8;
    dst[0]=v0.x; dst[1]=v0.y; dst[2]=v0.z; dst[3]=v0.w;
    dst[4]=v1.x; dst[5]=v1.y; dst[6]=v1.z; dst[7]=v1.w;
  }
  // decoder weight fragments: 12 slots x 64 lanes; each thread builds 3 sets.
  #pragma unroll
  for (int rep = 0; rep < 3; ++rep){
    const int s    = tid + rep*256;
    const int slot = s >> 6;
    const int l    = s & 63;
    const int bl_  = l & 15;
    const int gt_  = l >> 4;
    const float* src;
    if (slot < 8) src = m2w + (bl_ + 16*(slot>>1))*64 + 8*gt_ + 32*(slot&1);
    else { const int s2 = slot - 8;
           src = m3w + (bl_ + 16*(s2>>1))*64 + 8*gt_ + 32*(s2&1); }
    FragU hi, lo;
    expsplit8(src, hi, lo);
    fghi[slot][l] = hi.u4;
    fglo[slot][l] = lo.u4;
  }
  if (tid < 64){
    e1s2[tid]  = __expf(m1w[tid]) * TWO_LOG2E;
    m1b2s[tid] = m1b[tid] * TWO_LOG2E;
  }
  if (tid >= 64 && tid < 80){
    const int k = tid - 64;
    float acc = 0.f;
    #pragma unroll
    for (int d = 0; d < 32; ++d) acc += p1w[k*32 + d] * Wg[d];
    qsh[k]  = acc * TWO_LOG2E;
    pbb[k]  = p1b[k] * TWO_LOG2E;
    p2wn[k] = -2.f * p2w[k];
  }
  if (tid == 80){
    float A1 = 0.f, A2 = 0.f;
    #pragma unroll
    for (int d = 0; d < 32; ++d){ A1 += Wg[d]*ag[d]; A2 += Wg[d]*ag[32+d]; }
    scal[0] = A1 * LOG2E;
    scal[1] = A2 * LOG2E;
  }
  if (tid == 81){
    float sp = 0.f;
    #pragma unroll
    for (int k = 0; k < 16; ++k) sp += p2w[k];
    scal[2] = sp + p2b[0];
  }
  __syncthreads();

  // ---------------- staging phase B: u(c) table ----------------
  {
    const float u0 = scal[2];
    #pragma unroll
    for (int rep = 0; rep < 4; ++rep){
      const int n = tid + rep*256;
      const float c = TBL_LO + (float)n * (1.0f/TBL_SCALE);
      float u = u0;
      #pragma unroll
      for (int k = 0; k < 16; ++k){
        float E = ex2_(fmaf(c, qsh[k], pbb[k]));
        u = fmaf(p2wn[k], rcp_(E + 1.f), u);
      }
      tbl[n] = u * LOG2E;
    }
  }
  __syncthreads();

  // ---------------- attention: 8 i-rows per thread (packed f32x2) ----------
  const float A1p = scal[0], A2p = scal[1];
  const float* xrow = xsh + lb*33;
  f32x2 si2[4], s2[4], sx2[4];
  #pragma unroll
  for (int p = 0; p < 4; ++p){
    si2[p].x = A1p * xrow[q*8 + 2*p];
    si2[p].y = A1p * xrow[q*8 + 2*p + 1];
    s2[p] = (f32x2)(0.f);
    sx2[p] = (f32x2)(0.f);
  }
  #pragma unroll 4
  for (int j = 0; j < 32; ++j){
    const float xj = xrow[j];
    const float tj = A2p * xj;
    const f32x2 tj2 = { tj, tj };
    const f32x2 xj2 = { xj, xj };
    #pragma unroll
    for (int p = 0; p < 4; ++p){
      f32x2 v  = si2[p] + tj2;
      f32x2 l  = __builtin_elementwise_max(v, v * 0.2f);  // leaky_relu (log2e domain)
      f32x2 pe;
      pe.x = ex2_(l.x);
      pe.y = ex2_(l.y);
      s2[p]  = s2[p] + pe;
      sx2[p] = sx2[p] + pe * xj2;
    }
  }

  // ---------------- pooling via u(c) table + beta softmax + z_enc ----------
  float Zs = 0.f, Zd = 0.f;
  #pragma unroll
  for (int p = 0; p < 4; ++p){
    #pragma unroll
    for (int h = 0; h < 2; ++h){
      const float sv  = h ? s2[p].y  : s2[p].x;
      const float sxv = h ? sx2[p].y : sx2[p].x;
      const float c  = sxv * rcp_(sv);
      const float cc = fminf(fmaxf(c, TBL_LO), TBL_CMAX);
      const float f  = (cc - TBL_LO) * TBL_SCALE;
      const int   n  = (int)f;
      const float fr = f - (float)n;
      const float t0 = tbl[n];
      const float t1 = tbl[n + 1];
      const float u2 = fmaf(fr, t1 - t0, t0);
      const float eb = ex2_(u2);
      Zs = fmaf(eb, c, Zs);
      Zd += eb;
    }
  }
  Zs += __shfl_xor(Zs, 1);  Zd += __shfl_xor(Zd, 1);
  Zs += __shfl_xor(Zs, 2);  Zd += __shfl_xor(Zd, 2);
  const float Z = Zs * rcp_(Zd);

  if (valid){
    const float4 w0 = ((const float4*)Wg)[q*2 + 0];
    const float4 w1 = ((const float4*)Wg)[q*2 + 1];
    float4* o = (float4*)(out + (size_t)b*32 + q*8);
    o[0] = make_float4(Z*w0.x, Z*w0.y, Z*w0.z, Z*w0.w);
    o[1] = make_float4(Z*w1.x, Z*w1.y, Z*w1.z, Z*w1.w);
  }

  // ================= decoder (MFMA) =================
  const int lane = tid & 63;
  const int wv   = tid >> 6;
  const int gt   = lane >> 4;        // k-slice group (0..3)
  const int bl   = lane & 15;        // b within wave tile
  const int bd   = b0 + wv*16 + bl;
  const float sx0 = stx[(bd < B) ? bd : (B-1)];

  // --- h1 in B-fragment layout: B[k=g][n=b], lane owns b=bl, g=8*gt+j+32*kt
  uint32_t h1hi[2][4], h1lo[2][4];
  #pragma unroll
  for (int kt = 0; kt < 2; ++kt){
    const int g0 = 8*gt + 32*kt;
    float hv[8];
    #pragma unroll
    for (int j = 0; j < 8; ++j){
      float E = ex2_(fmaf(sx0, e1s2[g0+j], m1b2s[g0+j]));
      hv[j] = fmaf(-2.f, rcp_(E + 1.f), 1.f);     // tanh
    }
    #pragma unroll
    for (int jw = 0; jw < 4; ++jw)
      split2(hv[2*jw], hv[2*jw+1], h1hi[kt][jw], h1lo[kt][jw]);
  }

  // --- GEMM1: H2pre^T[h][b] = sum_g exp(m2w[h][g]) * h1[b][g]  (+ m2b[h])
  f32x4 acc[4];
  #pragma unroll
  for (int mt = 0; mt < 4; ++mt){
    float4 bi = *(const float4*)(m2b + 16*mt + 4*gt);
    acc[mt][0]=bi.x; acc[mt][1]=bi.y; acc[mt][2]=bi.z; acc[mt][3]=bi.w;
  }
  #pragma unroll
  for (int mt = 0; mt < 4; ++mt){
    #pragma unroll
    for (int kt = 0; kt < 2; ++kt){
      FragU Ahi, Alo, Bhi, Blo;
      Ahi.u4 = fghi[mt*2+kt][lane];
      Alo.u4 = fglo[mt*2+kt][lane];
      Bhi.w[0]=h1hi[kt][0]; Bhi.w[1]=h1hi[kt][1]; Bhi.w[2]=h1hi[kt][2]; Bhi.w[3]=h1hi[kt][3];
      Blo.w[0]=h1lo[kt][0]; Blo.w[1]=h1lo[kt][1]; Blo.w[2]=h1lo[kt][2]; Blo.w[3]=h1lo[kt][3];
      acc[mt] = __builtin_amdgcn_mfma_f32_16x16x32_bf16(Ahi.v, Bhi.v, acc[mt], 0, 0, 0);
      acc[mt] = __builtin_amdgcn_mfma_f32_16x16x32_bf16(Ahi.v, Blo.v, acc[mt], 0, 0, 0);
      acc[mt] = __builtin_amdgcn_mfma_f32_16x16x32_bf16(Alo.v, Bhi.v, acc[mt], 0, 0, 0);
    }
  }

  // --- tanh + pack: lane holds H2^T[h=16mt+4gt+r][b=bl]
  uint32_t Whi[4][2], Wlo[4][2];
  #pragma unroll
  for (int mt = 0; mt < 4; ++mt){
    float t0 = fmaf(-2.f, rcp_(ex2_(acc[mt][0]*TWO_LOG2E) + 1.f), 1.f);
    float t1 = fmaf(-2.f, rcp_(ex2_(acc[mt][1]*TWO_LOG2E) + 1.f), 1.f);
    float t2 = fmaf(-2.f, rcp_(ex2_(acc[mt][2]*TWO_LOG2E) + 1.f), 1.f);
    float t3 = fmaf(-2.f, rcp_(ex2_(acc[mt][3]*TWO_LOG2E) + 1.f), 1.f);
    split2(t0, t1, Whi[mt][0], Wlo[mt][0]);
    split2(t2, t3, Whi[mt][1], Wlo[mt][1]);
  }

  // --- cross-lane transpose into B-fragment layout for GEMM2
  FragU B2hi[2], B2lo[2];
  const int hiSel = gt >> 1;
  #pragma unroll
  for (int kt2 = 0; kt2 < 2; ++kt2){
    #pragma unroll
    for (int jw = 0; jw < 4; ++jw){
      const int sl = bl + 16*(((jw>>1) + 2*gt) & 3);
      const int w  = jw & 1;
      uint32_t c0 = (uint32_t)__shfl((int)Whi[2*kt2+0][w], sl);
      uint32_t c1 = (uint32_t)__shfl((int)Whi[2*kt2+1][w], sl);
      B2hi[kt2].w[jw] = hiSel ? c1 : c0;
      uint32_t d0 = (uint32_t)__shfl((int)Wlo[2*kt2+0][w], sl);
      uint32_t d1 = (uint32_t)__shfl((int)Wlo[2*kt2+1][w], sl);
      B2lo[kt2].w[jw] = hiSel ? d1 : d0;
    }
  }

  // --- GEMM2: Z^T[d][b] = sum_h exp(m3w[d][h]) * H2[b][h]  (+ m3b[d])
  f32x4 acc2[2];
  #pragma unroll
  for (int mt2 = 0; mt2 < 2; ++mt2){
    float4 bi = *(const float4*)(m3b + 16*mt2 + 4*gt);
    acc2[mt2][0]=bi.x; acc2[mt2][1]=bi.y; acc2[mt2][2]=bi.z; acc2[mt2][3]=bi.w;
  }
  #pragma unroll
  for (int mt2 = 0; mt2 < 2; ++mt2){
    #pragma unroll
    for (int kt2 = 0; kt2 < 2; ++kt2){
      FragU Ahi, Alo;
      Ahi.u4 = fghi[8 + mt2*2 + kt2][lane];
      Alo.u4 = fglo[8 + mt2*2 + kt2][lane];
      acc2[mt2] = __builtin_amdgcn_mfma_f32_16x16x32_bf16(Ahi.v, B2hi[kt2].v, acc2[mt2], 0, 0, 0);
      acc2[mt2] = __builtin_amdgcn_mfma_f32_16x16x32_bf16(Ahi.v, B2lo[kt2].v, acc2[mt2], 0, 0, 0);
      acc2[mt2] = __builtin_amdgcn_mfma_f32_16x16x32_bf16(Alo.v, B2hi[kt2].v, acc2[mt2], 0, 0, 0);
    }
  }

  // --- store z_dec
  if (bd < B){
    float* o = out + (size_t)B*32 + (size_t)bd*32;
    *(float4*)(o + 4*gt)      = make_float4(acc2[0][0], acc2[0][1], acc2[0][2], acc2[0][3]);
    *(float4*)(o + 16 + 4*gt) = make_float4(acc2[1][0], acc2[1][1], acc2[1][2], acc2[1][3]);
  }
}

extern "C" void kernel_launch(void* const* d_in, const int* in_sizes, int n_in,
                              void* d_out, int out_size, void* d_ws, size_t ws_size,
                              hipStream_t stream)
{
  const float* xs  = (const float*)d_in[0];
  const float* stx = (const float*)d_in[1];
  const float* Wg  = (const float*)d_in[2];
  const float* ag  = (const float*)d_in[3];
  const float* p1w = (const float*)d_in[4];
  const float* p1b = (const float*)d_in[5];
  const float* p2w = (const float*)d_in[6];
  const float* p2b = (const float*)d_in[7];
  const float* m1w = (const float*)d_in[8];
  const float* m1b = (const float*)d_in[9];
  const float* m2w = (const float*)d_in[10];
  const float* m2b = (const float*)d_in[11];
  const float* m3w = (const float*)d_in[12];
  const float* m3b = (const float*)d_in[13];
  float* out = (float*)d_out;
  const int B = in_sizes[0] / 32;
  const int nblk = (B + 63) / 64;
  hipLaunchKernelGGL(IDSSM_fused, dim3(nblk), dim3(256), 0, stream,
                     xs, stx, Wg, ag, p1w, p1b, p2w, p2b,
                     m1w, m1b, m2w, m2b, m3w, m3b, out, B);
}

// Round 7
// 26.517 us; speedup vs baseline: 3.1432x; 1.1844x over previous
//
#include <hip/hip_runtime.h>
#include <hip/hip_bf16.h>

#define LOG2E     1.4426950408889634f
#define TWO_LOG2E 2.8853900817779268f

typedef __attribute__((ext_vector_type(8))) short    bf16x8;
typedef __attribute__((ext_vector_type(8))) _Float16 f16x8;
typedef __attribute__((ext_vector_type(4))) float    f32x4;
typedef __attribute__((ext_vector_type(2))) float    f32x2;

__device__ __forceinline__ float rcp_(float x){ return __builtin_amdgcn_rcpf(x); }
__device__ __forceinline__ float ex2_(float x){ return __builtin_amdgcn_exp2f(x); }

union FragB { bf16x8 v; uint32_t w[4]; uint4 u4; };
union FragH { f16x8  v; uint32_t w[4]; uint4 u4; };

__device__ __forceinline__ uint16_t f2bf(float x){
  union { __hip_bfloat16 h; uint16_t u; } c; c.h = __float2bfloat16(x); return c.u;
}
__device__ __forceinline__ float bf2f(uint16_t u){
  union { __hip_bfloat16 h; uint16_t u; } c; c.u = u; return __bfloat162float(c.h);
}
__device__ __forceinline__ uint32_t pkh(float a, float b){
  union { _Float16 h; uint16_t u; } ca, cb;
  ca.h = (_Float16)a; cb.h = (_Float16)b;
  return (uint32_t)ca.u | ((uint32_t)cb.u << 16);
}
__device__ __forceinline__ void split2(float a, float b, uint32_t& whi, uint32_t& wlo){
  uint16_t ah = f2bf(a), bh = f2bf(b);
  uint16_t al = f2bf(a - bf2f(ah)), bl_ = f2bf(b - bf2f(bh));
  whi = (uint32_t)ah | ((uint32_t)bh << 16);
  wlo = (uint32_t)al | ((uint32_t)bl_ << 16);
}
__device__ __forceinline__ void expsplit8(const float* __restrict__ src,
                                          FragB& hi, FragB& lo){
  float4 a = *(const float4*)src;
  float4 b = *(const float4*)(src + 4);
  float e0=__expf(a.x), e1=__expf(a.y), e2=__expf(a.z), e3=__expf(a.w);
  float e4=__expf(b.x), e5=__expf(b.y), e6=__expf(b.z), e7=__expf(b.w);
  split2(e0,e1, hi.w[0], lo.w[0]);
  split2(e2,e3, hi.w[1], lo.w[1]);
  split2(e4,e5, hi.w[2], lo.w[2]);
  split2(e6,e7, hi.w[3], lo.w[3]);
}
// load 8 floats, exp(), convert to f16x8
__device__ __forceinline__ void exph8(const float* __restrict__ src, FragH& out){
  float4 a = *(const float4*)src;
  float4 b = *(const float4*)(src + 4);
  out.w[0] = pkh(__expf(a.x), __expf(a.y));
  out.w[1] = pkh(__expf(a.z), __expf(a.w));
  out.w[2] = pkh(__expf(b.x), __expf(b.y));
  out.w[3] = pkh(__expf(b.z), __expf(b.w));
}

#define TBL_N     512
#define TBL_SCALE 25.6f          // TBL_N / 20
#define TBL_LO    -10.0f
#define TBL_CMAX  9.9f

__global__ __launch_bounds__(256, 5) void IDSSM_fused(
    const float* __restrict__ xs,  const float* __restrict__ stx,
    const float* __restrict__ Wg,  const float* __restrict__ ag,
    const float* __restrict__ p1w, const float* __restrict__ p1b,
    const float* __restrict__ p2w, const float* __restrict__ p2b,
    const float* __restrict__ m1w, const float* __restrict__ m1b,
    const float* __restrict__ m2w, const float* __restrict__ m2b,
    const float* __restrict__ m3w, const float* __restrict__ m3b,
    float* __restrict__ out, int B)
{
  __shared__ float xsh[64*33];       // x rows, padded stride 33 (8.25 KB)
  __shared__ uint4 fg1[8][64];       // GEMM1 A frags, f16 single (8 KB)
  __shared__ uint4 fg2hi[4][64];     // GEMM2 A frags bf16 hi (4 KB)
  __shared__ uint4 fg2lo[4][64];     // GEMM2 A frags bf16 lo (4 KB)
  __shared__ float tbl[TBL_N];       // u(c)*log2e PWL table (2 KB)
  __shared__ float e1s2[64];         // exp(m1_w)*2log2e
  __shared__ float m1b2s[64];        // m1_b*2log2e
  __shared__ float qsh[16];          // (p1_w @ W_gat)*2log2e
  __shared__ float pbb[16];          // p1_b*2log2e
  __shared__ float p2wn[16];         // -2*p2w
  __shared__ float scal[3];          // A1*log2e, A2*log2e, p2b0+sum(p2w)

  const int tid = threadIdx.x;
  const int lb  = tid >> 2;          // local b (0..63)
  const int q   = tid & 3;           // quarter (0..3)
  const int b0  = blockIdx.x * 64;
  const int b   = b0 + lb;
  const bool valid = (b < B);

  const int lane = tid & 63;
  const int bl_  = lane & 15;
  const int gt_  = lane >> 4;

  // ---------------- staging phase A ----------------
  { // x rows into padded LDS
    int rsrc = b0 + lb; if (rsrc >= B) rsrc = B - 1;
    const float4* src = (const float4*)(xs + (size_t)rsrc*32) + q*2;
    float4 v0 = src[0], v1 = src[1];
    float* dst = xsh + lb*33 + q*8;
    dst[0]=v0.x; dst[1]=v0.y; dst[2]=v0.z; dst[3]=v0.w;
    dst[4]=v1.x; dst[5]=v1.y; dst[6]=v1.z; dst[7]=v1.w;
  }
  // GEMM1 A fragments (f16 single): slots 0..7, slot = mt*2+kt
  #pragma unroll
  for (int rep = 0; rep < 2; ++rep){
    const int s  = (tid >> 6) + 4*rep;
    const int mt = s >> 1, kt = s & 1;
    FragH h;
    exph8(m2w + (bl_ + 16*mt)*64 + 8*gt_ + 32*kt, h);
    fg1[s][lane] = h.u4;
  }
  { // GEMM2 A fragments (bf16 hi/lo): slots 0..3, slot = mt2*2+kt2
    const int s2  = tid >> 6;
    const int mt2 = s2 >> 1, kt2 = s2 & 1;
    FragB hi, lo;
    expsplit8(m3w + (bl_ + 16*mt2)*64 + 8*gt_ + 32*kt2, hi, lo);
    fg2hi[s2][lane] = hi.u4;
    fg2lo[s2][lane] = lo.u4;
  }
  if (tid < 64){
    e1s2[tid]  = __expf(m1w[tid]) * TWO_LOG2E;
    m1b2s[tid] = m1b[tid] * TWO_LOG2E;
  }
  if (tid >= 64 && tid < 80){
    const int k = tid - 64;
    float acc = 0.f;
    #pragma unroll
    for (int d = 0; d < 32; ++d) acc += p1w[k*32 + d] * Wg[d];
    qsh[k]  = acc * TWO_LOG2E;
    pbb[k]  = p1b[k] * TWO_LOG2E;
    p2wn[k] = -2.f * p2w[k];
  }
  if (tid == 80){
    float A1 = 0.f, A2 = 0.f;
    #pragma unroll
    for (int d = 0; d < 32; ++d){ A1 += Wg[d]*ag[d]; A2 += Wg[d]*ag[32+d]; }
    scal[0] = A1 * LOG2E;
    scal[1] = A2 * LOG2E;
  }
  if (tid == 81){
    float sp = 0.f;
    #pragma unroll
    for (int k = 0; k < 16; ++k) sp += p2w[k];
    scal[2] = sp + p2b[0];
  }
  __syncthreads();

  // ---------------- staging phase B: u(c) table (512 entries) --------------
  {
    const float u0 = scal[2];
    #pragma unroll
    for (int rep = 0; rep < 2; ++rep){
      const int n = tid + rep*256;
      const float c = TBL_LO + (float)n * (1.0f/TBL_SCALE);
      float u = u0;
      #pragma unroll
      for (int k = 0; k < 16; ++k){
        float E = ex2_(fmaf(c, qsh[k], pbb[k]));
        u = fmaf(p2wn[k], rcp_(E + 1.f), u);
      }
      tbl[n] = u * LOG2E;
    }
  }
  __syncthreads();

  // ---------------- attention (factorized): 8 i-rows per thread ------------
  // p_ij = exp2(lrelu(si+tj)) = max( exp2(si)*exp2(tj), exp2(.2si)*exp2(.2tj) )
  const float A1p = scal[0], A2p = scal[1];
  const float* xrow = xsh + lb*33;
  f32x2 Ei2[4], Eq2[4], s2[4], sx2[4];
  #pragma unroll
  for (int p = 0; p < 4; ++p){
    float sa = A1p * xrow[q*8 + 2*p];
    float sb = A1p * xrow[q*8 + 2*p + 1];
    Ei2[p] = (f32x2){ ex2_(sa), ex2_(sb) };
    Eq2[p] = (f32x2){ ex2_(0.2f*sa), ex2_(0.2f*sb) };
    s2[p]  = (f32x2)(0.f);
    sx2[p] = (f32x2)(0.f);
  }
  #pragma unroll 4
  for (int j = 0; j < 32; ++j){
    const float xj = xrow[j];
    const float tj = A2p * xj;
    const float Fj = ex2_(tj);
    const float Fq = ex2_(0.2f*tj);
    const f32x2 Fj2 = { Fj, Fj };
    const f32x2 Fq2 = { Fq, Fq };
    const f32x2 xj2 = { xj, xj };
    #pragma unroll
    for (int p = 0; p < 4; ++p){
      f32x2 pa = Ei2[p] * Fj2;
      f32x2 pb = Eq2[p] * Fq2;
      f32x2 pe = __builtin_elementwise_max(pa, pb);
      s2[p]  = s2[p] + pe;
      sx2[p] = sx2[p] + pe * xj2;
    }
  }

  // ---------------- pooling via u(c) table + beta softmax + z_enc ----------
  float Zs = 0.f, Zd = 0.f;
  #pragma unroll
  for (int p = 0; p < 4; ++p){
    #pragma unroll
    for (int h = 0; h < 2; ++h){
      const float sv  = h ? s2[p].y  : s2[p].x;
      const float sxv = h ? sx2[p].y : sx2[p].x;
      const float c  = sxv * rcp_(sv);
      const float cc = fminf(fmaxf(c, TBL_LO), TBL_CMAX);
      const float f  = (cc - TBL_LO) * TBL_SCALE;
      const int   n  = (int)f;
      const float fr = f - (float)n;
      const float t0 = tbl[n];
      const float t1 = tbl[n + 1];
      const float u2 = fmaf(fr, t1 - t0, t0);
      const float eb = ex2_(u2);
      Zs = fmaf(eb, c, Zs);
      Zd += eb;
    }
  }
  Zs += __shfl_xor(Zs, 1);  Zd += __shfl_xor(Zd, 1);
  Zs += __shfl_xor(Zs, 2);  Zd += __shfl_xor(Zd, 2);
  const float Z = Zs * rcp_(Zd);

  if (valid){
    const float4 w0 = ((const float4*)Wg)[q*2 + 0];
    const float4 w1 = ((const float4*)Wg)[q*2 + 1];
    float4* o = (float4*)(out + (size_t)b*32 + q*8);
    o[0] = make_float4(Z*w0.x, Z*w0.y, Z*w0.z, Z*w0.w);
    o[1] = make_float4(Z*w1.x, Z*w1.y, Z*w1.z, Z*w1.w);
  }

  // ================= decoder (MFMA) =================
  const int wv = tid >> 6;
  const int gt = gt_;                // k-slice group (0..3)
  const int bl = bl_;                // b within wave tile
  const int bd = b0 + wv*16 + bl;
  const float sx0 = stx[(bd < B) ? bd : (B-1)];

  // --- h1 in f16 B-fragment layout: lane owns b=bl, g=8*gt+j+32*kt
  FragH h1f[2];
  #pragma unroll
  for (int kt = 0; kt < 2; ++kt){
    const int g0 = 8*gt + 32*kt;
    float hv[8];
    #pragma unroll
    for (int j = 0; j < 8; ++j){
      float E = ex2_(fmaf(sx0, e1s2[g0+j], m1b2s[g0+j]));
      hv[j] = fmaf(-2.f, rcp_(E + 1.f), 1.f);     // tanh
    }
    #pragma unroll
    for (int jw = 0; jw < 4; ++jw)
      h1f[kt].w[jw] = pkh(hv[2*jw], hv[2*jw+1]);
  }

  // --- GEMM1 (f16): H2pre^T[h][b] = sum_g exp(m2w[h][g]) * h1[b][g] + m2b[h]
  f32x4 acc[4];
  #pragma unroll
  for (int mt = 0; mt < 4; ++mt){
    float4 bi = *(const float4*)(m2b + 16*mt + 4*gt);
    acc[mt][0]=bi.x; acc[mt][1]=bi.y; acc[mt][2]=bi.z; acc[mt][3]=bi.w;
  }
  #pragma unroll
  for (int mt = 0; mt < 4; ++mt){
    #pragma unroll
    for (int kt = 0; kt < 2; ++kt){
      FragH A; A.u4 = fg1[mt*2+kt][lane];
      acc[mt] = __builtin_amdgcn_mfma_f32_16x16x32_f16(A.v, h1f[kt].v, acc[mt], 0, 0, 0);
    }
  }

  // --- tanh + bf16 hi/lo pack: lane holds H2^T[h=16mt+4gt+r][b=bl]
  uint32_t Whi[4][2], Wlo[4][2];
  #pragma unroll
  for (int mt = 0; mt < 4; ++mt){
    float t0 = fmaf(-2.f, rcp_(ex2_(acc[mt][0]*TWO_LOG2E) + 1.f), 1.f);
    float t1 = fmaf(-2.f, rcp_(ex2_(acc[mt][1]*TWO_LOG2E) + 1.f), 1.f);
    float t2 = fmaf(-2.f, rcp_(ex2_(acc[mt][2]*TWO_LOG2E) + 1.f), 1.f);
    float t3 = fmaf(-2.f, rcp_(ex2_(acc[mt][3]*TWO_LOG2E) + 1.f), 1.f);
    split2(t0, t1, Whi[mt][0], Wlo[mt][0]);
    split2(t2, t3, Whi[mt][1], Wlo[mt][1]);
  }

  // --- cross-lane transpose into bf16 B-fragment layout for GEMM2
  FragB B2hi[2], B2lo[2];
  const int hiSel = gt >> 1;
  #pragma unroll
  for (int kt2 = 0; kt2 < 2; ++kt2){
    #pragma unroll
    for (int jw = 0; jw < 4; ++jw){
      const int sl = bl + 16*(((jw>>1) + 2*gt) & 3);
      const int w  = jw & 1;
      uint32_t c0 = (uint32_t)__shfl((int)Whi[2*kt2+0][w], sl);
      uint32_t c1 = (uint32_t)__shfl((int)Whi[2*kt2+1][w], sl);
      B2hi[kt2].w[jw] = hiSel ? c1 : c0;
      uint32_t d0 = (uint32_t)__shfl((int)Wlo[2*kt2+0][w], sl);
      uint32_t d1 = (uint32_t)__shfl((int)Wlo[2*kt2+1][w], sl);
      B2lo[kt2].w[jw] = hiSel ? d1 : d0;
    }
  }

  // --- GEMM2 (bf16 hi/lo): Z^T[d][b] = sum_h exp(m3w[d][h]) * H2[b][h] + m3b[d]
  f32x4 acc2[2];
  #pragma unroll
  for (int mt2 = 0; mt2 < 2; ++mt2){
    float4 bi = *(const float4*)(m3b + 16*mt2 + 4*gt);
    acc2[mt2][0]=bi.x; acc2[mt2][1]=bi.y; acc2[mt2][2]=bi.z; acc2[mt2][3]=bi.w;
  }
  #pragma unroll
  for (int mt2 = 0; mt2 < 2; ++mt2){
    #pragma unroll
    for (int kt2 = 0; kt2 < 2; ++kt2){
      FragB Ahi, Alo;
      Ahi.u4 = fg2hi[mt2*2 + kt2][lane];
      Alo.u4 = fg2lo[mt2*2 + kt2][lane];
      acc2[mt2] = __builtin_amdgcn_mfma_f32_16x16x32_bf16(Ahi.v, B2hi[kt2].v, acc2[mt2], 0, 0, 0);
      acc2[mt2] = __builtin_amdgcn_mfma_f32_16x16x32_bf16(Ahi.v, B2lo[kt2].v, acc2[mt2], 0, 0, 0);
      acc2[mt2] = __builtin_amdgcn_mfma_f32_16x16x32_bf16(Alo.v, B2hi[kt2].v, acc2[mt2], 0, 0, 0);
    }
  }

  // --- store z_dec
  if (bd < B){
    float* o = out + (size_t)B*32 + (size_t)bd*32;
    *(float4*)(o + 4*gt)      = make_float4(acc2[0][0], acc2[0][1], acc2[0][2], acc2[0][3]);
    *(float4*)(o + 16 + 4*gt) = make_float4(acc2[1][0], acc2[1][1], acc2[1][2], acc2[1][3]);
  }
}

extern "C" void kernel_launch(void* const* d_in, const int* in_sizes, int n_in,
                              void* d_out, int out_size, void* d_ws, size_t ws_size,
                              hipStream_t stream)
{
  const float* xs  = (const float*)d_in[0];
  const float* stx = (const float*)d_in[1];
  const float* Wg  = (const float*)d_in[2];
  const float* ag  = (const float*)d_in[3];
  const float* p1w = (const float*)d_in[4];
  const float* p1b = (const float*)d_in[5];
  const float* p2w = (const float*)d_in[6];
  const float* p2b = (const float*)d_in[7];
  const float* m1w = (const float*)d_in[8];
  const float* m1b = (const float*)d_in[9];
  const float* m2w = (const float*)d_in[10];
  const float* m2b = (const float*)d_in[11];
  const float* m3w = (const float*)d_in[12];
  const float* m3b = (const float*)d_in[13];
  float* out = (float*)d_out;
  const int B = in_sizes[0] / 32;
  const int nblk = (B + 63) / 64;
  hipLaunchKernelGGL(IDSSM_fused, dim3(nblk), dim3(256), 0, stream,
                     xs, stx, Wg, ag, p1w, p1b, p2w, p2b,
                     m1w, m1b, m2w, m2b, m3w, m3b, out, B);
}

// Round 8
// 25.736 us; speedup vs baseline: 3.2386x; 1.0304x over previous
//
#include <hip/hip_runtime.h>
#include <hip/hip_bf16.h>

#define LOG2E     1.4426950408889634f
#define TWO_LOG2E 2.8853900817779268f

typedef __attribute__((ext_vector_type(8))) short    bf16x8;
typedef __attribute__((ext_vector_type(8))) _Float16 f16x8;
typedef __attribute__((ext_vector_type(4))) float    f32x4;
typedef __attribute__((ext_vector_type(2))) float    f32x2;

__device__ __forceinline__ float rcp_(float x){ return __builtin_amdgcn_rcpf(x); }
__device__ __forceinline__ float ex2_(float x){ return __builtin_amdgcn_exp2f(x); }

// quad broadcast: every 4-lane group reads lane K of the group (DPP quad_perm)
template<int K>
__device__ __forceinline__ float quadbc(float v){
  constexpr int ctrl = K * 0x55;   // quad_perm [K,K,K,K]
  return __int_as_float(__builtin_amdgcn_mov_dpp(__float_as_int(v), ctrl, 0xf, 0xf, true));
}

union FragB { bf16x8 v; uint32_t w[4]; uint4 u4; };
union FragH { f16x8  v; uint32_t w[4]; uint4 u4; };

__device__ __forceinline__ uint16_t f2bf(float x){
  union { __hip_bfloat16 h; uint16_t u; } c; c.h = __float2bfloat16(x); return c.u;
}
__device__ __forceinline__ float bf2f(uint16_t u){
  union { __hip_bfloat16 h; uint16_t u; } c; c.u = u; return __bfloat162float(c.h);
}
__device__ __forceinline__ uint32_t pkh(float a, float b){
  union { _Float16 h; uint16_t u; } ca, cb;
  ca.h = (_Float16)a; cb.h = (_Float16)b;
  return (uint32_t)ca.u | ((uint32_t)cb.u << 16);
}
__device__ __forceinline__ void split2(float a, float b, uint32_t& whi, uint32_t& wlo){
  uint16_t ah = f2bf(a), bh = f2bf(b);
  uint16_t al = f2bf(a - bf2f(ah)), bl_ = f2bf(b - bf2f(bh));
  whi = (uint32_t)ah | ((uint32_t)bh << 16);
  wlo = (uint32_t)al | ((uint32_t)bl_ << 16);
}
__device__ __forceinline__ void expsplit8(const float* __restrict__ src,
                                          FragB& hi, FragB& lo){
  float4 a = *(const float4*)src;
  float4 b = *(const float4*)(src + 4);
  float e0=__expf(a.x), e1=__expf(a.y), e2=__expf(a.z), e3=__expf(a.w);
  float e4=__expf(b.x), e5=__expf(b.y), e6=__expf(b.z), e7=__expf(b.w);
  split2(e0,e1, hi.w[0], lo.w[0]);
  split2(e2,e3, hi.w[1], lo.w[1]);
  split2(e4,e5, hi.w[2], lo.w[2]);
  split2(e6,e7, hi.w[3], lo.w[3]);
}
__device__ __forceinline__ void exph8(const float* __restrict__ src, FragH& out){
  float4 a = *(const float4*)src;
  float4 b = *(const float4*)(src + 4);
  out.w[0] = pkh(__expf(a.x), __expf(a.y));
  out.w[1] = pkh(__expf(a.z), __expf(a.w));
  out.w[2] = pkh(__expf(b.x), __expf(b.y));
  out.w[3] = pkh(__expf(b.z), __expf(b.w));
}

// ws layout (float offsets)
#define WS_FG1   0        // 8 slots x 64 lanes x uint4 = 2048 floats
#define WS_FG2H  2048     // 4 x 64 x uint4 = 1024
#define WS_FG2L  3072     // 1024
#define WS_TBL   4096     // 512
#define WS_E1S   4608     // 64  exp(m1_w)*2log2e
#define WS_M1B   4672     // 64  m1_b*2log2e
#define WS_SCAL  4736     // 2   A1*log2e, A2*log2e

#define TBL_N     512
#define TBL_SCALE 25.6f
#define TBL_LO    -10.0f
#define TBL_CMAX  9.9f

__global__ __launch_bounds__(256) void IDSSM_pre(
    const float* __restrict__ Wg,  const float* __restrict__ ag,
    const float* __restrict__ p1w, const float* __restrict__ p1b,
    const float* __restrict__ p2w, const float* __restrict__ p2b,
    const float* __restrict__ m1w, const float* __restrict__ m1b,
    const float* __restrict__ m2w, const float* __restrict__ m3w,
    float* __restrict__ ws)
{
  const int blk = blockIdx.x;
  const int tid = threadIdx.x;
  const int l  = tid & 63;
  const int bl = l & 15, gt = l >> 4;
  if (blk < 2){
    const int s  = (blk*256 + tid) >> 6;   // slot 0..7 = mt*2+kt
    const int mt = s >> 1, kt = s & 1;
    FragH h;
    exph8(m2w + (bl + 16*mt)*64 + 8*gt + 32*kt, h);
    *(uint4*)(ws + WS_FG1 + (size_t)(s*64 + l)*4) = h.u4;
  } else if (blk == 2){
    const int s2  = tid >> 6;              // slot 0..3 = mt2*2+kt2
    const int mt2 = s2 >> 1, kt2 = s2 & 1;
    FragB hi, lo;
    expsplit8(m3w + (bl + 16*mt2)*64 + 8*gt + 32*kt2, hi, lo);
    *(uint4*)(ws + WS_FG2H + (size_t)(s2*64 + l)*4) = hi.u4;
    *(uint4*)(ws + WS_FG2L + (size_t)(s2*64 + l)*4) = lo.u4;
  } else if (blk == 3){
    __shared__ float qs[16], pb_[16], pw[16], u0s[1];
    if (tid < 16){
      float acc = 0.f;
      #pragma unroll
      for (int d = 0; d < 32; ++d) acc += p1w[tid*32 + d] * Wg[d];
      qs[tid]  = acc * TWO_LOG2E;
      pb_[tid] = p1b[tid] * TWO_LOG2E;
      pw[tid]  = -2.f * p2w[tid];
    }
    if (tid == 16){
      float sp = 0.f;
      #pragma unroll
      for (int k = 0; k < 16; ++k) sp += p2w[k];
      u0s[0] = sp + p2b[0];
    }
    __syncthreads();
    #pragma unroll
    for (int rep = 0; rep < 2; ++rep){
      const int n = tid + rep*256;
      const float c = TBL_LO + (float)n * (1.0f/TBL_SCALE);
      float u = u0s[0];
      #pragma unroll
      for (int k = 0; k < 16; ++k){
        float E = ex2_(fmaf(c, qs[k], pb_[k]));
        u = fmaf(pw[k], rcp_(E + 1.f), u);
      }
      ws[WS_TBL + n] = u * LOG2E;
    }
  } else {
    if (tid < 64){
      ws[WS_E1S + tid] = __expf(m1w[tid]) * TWO_LOG2E;
      ws[WS_M1B + tid] = m1b[tid] * TWO_LOG2E;
    } else if (tid == 64){
      float A1 = 0.f, A2 = 0.f;
      #pragma unroll
      for (int d = 0; d < 32; ++d){ A1 += Wg[d]*ag[d]; A2 += Wg[d]*ag[32+d]; }
      ws[WS_SCAL + 0] = A1 * LOG2E;
      ws[WS_SCAL + 1] = A2 * LOG2E;
    }
  }
}

#define XJ(J) (((((J)&3))==0) ? xr4[(J)>>2].x : ((((J)&3))==1) ? xr4[(J)>>2].y : \
               ((((J)&3))==2) ? xr4[(J)>>2].z : xr4[(J)>>2].w)

#define ATT_J(JQ, JR) { \
    const float Fj_ = quadbc<JQ>(Fjr[JR]); \
    const float Fq_ = quadbc<JQ>(Fqr[JR]); \
    const float xj_ = XJ(JQ*8+JR); \
    const f32x2 Fj2_ = {Fj_,Fj_}, Fq2_ = {Fq_,Fq_}, xj2_ = {xj_,xj_}; \
    f32x2 pe_; \
    pe_ = __builtin_elementwise_max(Ei2[0]*Fj2_, Eq2[0]*Fq2_); s2[0] = s2[0] + pe_; sx2[0] = sx2[0] + pe_*xj2_; \
    pe_ = __builtin_elementwise_max(Ei2[1]*Fj2_, Eq2[1]*Fq2_); s2[1] = s2[1] + pe_; sx2[1] = sx2[1] + pe_*xj2_; \
    pe_ = __builtin_elementwise_max(Ei2[2]*Fj2_, Eq2[2]*Fq2_); s2[2] = s2[2] + pe_; sx2[2] = sx2[2] + pe_*xj2_; \
    pe_ = __builtin_elementwise_max(Ei2[3]*Fj2_, Eq2[3]*Fq2_); s2[3] = s2[3] + pe_; sx2[3] = sx2[3] + pe_*xj2_; \
  }
#define ATT_Q(JQ) ATT_J(JQ,0) ATT_J(JQ,1) ATT_J(JQ,2) ATT_J(JQ,3) \
                  ATT_J(JQ,4) ATT_J(JQ,5) ATT_J(JQ,6) ATT_J(JQ,7)

__global__ __launch_bounds__(256, 4) void IDSSM_main(
    const float* __restrict__ xs,  const float* __restrict__ stx,
    const float* __restrict__ Wg,  const float* __restrict__ m2b,
    const float* __restrict__ m3b, const float* __restrict__ ws,
    float* __restrict__ out, int B)
{
  __shared__ float tbl[TBL_N];
  const int tid = threadIdx.x;
  const int lb  = tid >> 2;          // local b (0..63)
  const int q   = tid & 3;           // quarter
  const int b0  = blockIdx.x * 64;
  const int b   = b0 + lb;
  const bool valid = (b < B);
  const int rsrc = valid ? b : (B - 1);

  // ---- early loads: table slice, scalars, own x row ----
  const float2 tco = *(const float2*)(ws + WS_TBL + tid*2);
  const float A1p = ws[WS_SCAL + 0];
  const float A2p = ws[WS_SCAL + 1];

  const float4* xrow4 = (const float4*)(xs + (size_t)rsrc*32);
  float4 xr4[8];
  #pragma unroll
  for (int t = 0; t < 8; ++t) xr4[t] = xrow4[t];
  float4 xia = xrow4[q*2], xib = xrow4[q*2 + 1];   // own i-slice (runtime addr, static regs)
  float xi[8] = { xia.x, xia.y, xia.z, xia.w, xib.x, xib.y, xib.z, xib.w };

  // park table slice in LDS (barrier comes after attention)
  tbl[tid*2]     = tco.x;
  tbl[tid*2 + 1] = tco.y;

  // ---- attention (factorized, quad-shared Fj/Fq via DPP) ----
  float Fjr[8], Fqr[8];
  #pragma unroll
  for (int t = 0; t < 8; ++t){
    const float tv = A2p * xi[t];
    Fjr[t] = ex2_(tv);
    Fqr[t] = ex2_(0.2f * tv);
  }
  f32x2 Ei2[4], Eq2[4], s2[4], sx2[4];
  #pragma unroll
  for (int p = 0; p < 4; ++p){
    const float sa = A1p * xi[2*p], sb = A1p * xi[2*p + 1];
    Ei2[p] = (f32x2){ ex2_(sa), ex2_(sb) };
    Eq2[p] = (f32x2){ ex2_(0.2f*sa), ex2_(0.2f*sb) };
    s2[p]  = (f32x2)(0.f);
    sx2[p] = (f32x2)(0.f);
  }
  ATT_Q(0) ATT_Q(1) ATT_Q(2) ATT_Q(3)

  __syncthreads();   // tbl ready (writes above), all waves past attention

  // ---- pooling via u(c) table + beta softmax + z_enc ----
  float Zs = 0.f, Zd = 0.f;
  #pragma unroll
  for (int p = 0; p < 4; ++p){
    #pragma unroll
    for (int h = 0; h < 2; ++h){
      const float sv  = h ? s2[p].y  : s2[p].x;
      const float sxv = h ? sx2[p].y : sx2[p].x;
      const float c  = sxv * rcp_(sv);
      const float cc = fminf(fmaxf(c, TBL_LO), TBL_CMAX);
      const float f  = (cc - TBL_LO) * TBL_SCALE;
      const int   n  = (int)f;
      const float fr = f - (float)n;
      const float t0 = tbl[n];
      const float t1 = tbl[n + 1];
      const float eb = ex2_(fmaf(fr, t1 - t0, t0));
      Zs = fmaf(eb, c, Zs);
      Zd += eb;
    }
  }
  Zs += __shfl_xor(Zs, 1);  Zd += __shfl_xor(Zd, 1);
  Zs += __shfl_xor(Zs, 2);  Zd += __shfl_xor(Zd, 2);
  const float Z = Zs * rcp_(Zd);

  if (valid){
    const float4 w0 = ((const float4*)Wg)[q*2 + 0];
    const float4 w1 = ((const float4*)Wg)[q*2 + 1];
    float4* o = (float4*)(out + (size_t)b*32 + q*8);
    o[0] = make_float4(Z*w0.x, Z*w0.y, Z*w0.z, Z*w0.w);
    o[1] = make_float4(Z*w1.x, Z*w1.y, Z*w1.z, Z*w1.w);
  }

  // ================= decoder (MFMA, frags from ws/L2) =================
  const int lane = tid & 63;
  const int wv   = tid >> 6;
  const int gt   = lane >> 4;
  const int bl   = lane & 15;
  const int bd   = b0 + wv*16 + bl;
  const float sx0 = stx[(bd < B) ? bd : (B-1)];

  // issue GEMM1 frag loads (L2) — consumed after h1 compute
  uint4 fg1r[8];
  #pragma unroll
  for (int s = 0; s < 8; ++s)
    fg1r[s] = *(const uint4*)(ws + WS_FG1 + (size_t)(s*64 + lane)*4);

  // h1 in f16 B-fragment layout
  FragH h1f[2];
  #pragma unroll
  for (int kt = 0; kt < 2; ++kt){
    const int g0 = 8*gt + 32*kt;
    const float4* e1p = (const float4*)(ws + WS_E1S + g0);
    const float4* m1p = (const float4*)(ws + WS_M1B + g0);
    float4 ea = e1p[0], eb4 = e1p[1];
    float4 ma = m1p[0], mb4 = m1p[1];
    float ev[8] = { ea.x,ea.y,ea.z,ea.w, eb4.x,eb4.y,eb4.z,eb4.w };
    float mv[8] = { ma.x,ma.y,ma.z,ma.w, mb4.x,mb4.y,mb4.z,mb4.w };
    float hv[8];
    #pragma unroll
    for (int j = 0; j < 8; ++j){
      float E = ex2_(fmaf(sx0, ev[j], mv[j]));
      hv[j] = fmaf(-2.f, rcp_(E + 1.f), 1.f);     // tanh
    }
    #pragma unroll
    for (int jw = 0; jw < 4; ++jw)
      h1f[kt].w[jw] = pkh(hv[2*jw], hv[2*jw+1]);
  }

  // GEMM1 (f16): H2pre^T[h][b] = sum_g exp(m2w[h][g]) * h1[b][g] + m2b[h]
  f32x4 acc[4];
  #pragma unroll
  for (int mt = 0; mt < 4; ++mt){
    float4 bi = *(const float4*)(m2b + 16*mt + 4*gt);
    acc[mt][0]=bi.x; acc[mt][1]=bi.y; acc[mt][2]=bi.z; acc[mt][3]=bi.w;
  }
  #pragma unroll
  for (int mt = 0; mt < 4; ++mt){
    #pragma unroll
    for (int kt = 0; kt < 2; ++kt){
      FragH A; A.u4 = fg1r[mt*2 + kt];
      acc[mt] = __builtin_amdgcn_mfma_f32_16x16x32_f16(A.v, h1f[kt].v, acc[mt], 0, 0, 0);
    }
  }

  // issue GEMM2 frag loads (L2) — consumed after tanh+transpose
  uint4 fg2h[4], fg2l[4];
  #pragma unroll
  for (int s = 0; s < 4; ++s){
    fg2h[s] = *(const uint4*)(ws + WS_FG2H + (size_t)(s*64 + lane)*4);
    fg2l[s] = *(const uint4*)(ws + WS_FG2L + (size_t)(s*64 + lane)*4);
  }

  // tanh + bf16 hi/lo pack
  uint32_t Whi[4][2], Wlo[4][2];
  #pragma unroll
  for (int mt = 0; mt < 4; ++mt){
    float t0 = fmaf(-2.f, rcp_(ex2_(acc[mt][0]*TWO_LOG2E) + 1.f), 1.f);
    float t1 = fmaf(-2.f, rcp_(ex2_(acc[mt][1]*TWO_LOG2E) + 1.f), 1.f);
    float t2 = fmaf(-2.f, rcp_(ex2_(acc[mt][2]*TWO_LOG2E) + 1.f), 1.f);
    float t3 = fmaf(-2.f, rcp_(ex2_(acc[mt][3]*TWO_LOG2E) + 1.f), 1.f);
    split2(t0, t1, Whi[mt][0], Wlo[mt][0]);
    split2(t2, t3, Whi[mt][1], Wlo[mt][1]);
  }

  // cross-lane transpose into bf16 B-fragment layout for GEMM2
  FragB B2hi[2], B2lo[2];
  const int hiSel = gt >> 1;
  #pragma unroll
  for (int kt2 = 0; kt2 < 2; ++kt2){
    #pragma unroll
    for (int jw = 0; jw < 4; ++jw){
      const int sl = bl + 16*(((jw>>1) + 2*gt) & 3);
      const int w  = jw & 1;
      uint32_t c0 = (uint32_t)__shfl((int)Whi[2*kt2+0][w], sl);
      uint32_t c1 = (uint32_t)__shfl((int)Whi[2*kt2+1][w], sl);
      B2hi[kt2].w[jw] = hiSel ? c1 : c0;
      uint32_t d0 = (uint32_t)__shfl((int)Wlo[2*kt2+0][w], sl);
      uint32_t d1 = (uint32_t)__shfl((int)Wlo[2*kt2+1][w], sl);
      B2lo[kt2].w[jw] = hiSel ? d1 : d0;
    }
  }

  // GEMM2 (bf16 hi/lo): Z^T[d][b] = sum_h exp(m3w[d][h]) * H2[b][h] + m3b[d]
  f32x4 acc2[2];
  #pragma unroll
  for (int mt2 = 0; mt2 < 2; ++mt2){
    float4 bi = *(const float4*)(m3b + 16*mt2 + 4*gt);
    acc2[mt2][0]=bi.x; acc2[mt2][1]=bi.y; acc2[mt2][2]=bi.z; acc2[mt2][3]=bi.w;
  }
  #pragma unroll
  for (int mt2 = 0; mt2 < 2; ++mt2){
    #pragma unroll
    for (int kt2 = 0; kt2 < 2; ++kt2){
      FragB Ahi, Alo;
      Ahi.u4 = fg2h[mt2*2 + kt2];
      Alo.u4 = fg2l[mt2*2 + kt2];
      acc2[mt2] = __builtin_amdgcn_mfma_f32_16x16x32_bf16(Ahi.v, B2hi[kt2].v, acc2[mt2], 0, 0, 0);
      acc2[mt2] = __builtin_amdgcn_mfma_f32_16x16x32_bf16(Ahi.v, B2lo[kt2].v, acc2[mt2], 0, 0, 0);
      acc2[mt2] = __builtin_amdgcn_mfma_f32_16x16x32_bf16(Alo.v, B2hi[kt2].v, acc2[mt2], 0, 0, 0);
    }
  }

  if (bd < B){
    float* o = out + (size_t)B*32 + (size_t)bd*32;
    *(float4*)(o + 4*gt)      = make_float4(acc2[0][0], acc2[0][1], acc2[0][2], acc2[0][3]);
    *(float4*)(o + 16 + 4*gt) = make_float4(acc2[1][0], acc2[1][1], acc2[1][2], acc2[1][3]);
  }
}

extern "C" void kernel_launch(void* const* d_in, const int* in_sizes, int n_in,
                              void* d_out, int out_size, void* d_ws, size_t ws_size,
                              hipStream_t stream)
{
  const float* xs  = (const float*)d_in[0];
  const float* stx = (const float*)d_in[1];
  const float* Wg  = (const float*)d_in[2];
  const float* ag  = (const float*)d_in[3];
  const float* p1w = (const float*)d_in[4];
  const float* p1b = (const float*)d_in[5];
  const float* p2w = (const float*)d_in[6];
  const float* p2b = (const float*)d_in[7];
  const float* m1w = (const float*)d_in[8];
  const float* m1b = (const float*)d_in[9];
  const float* m2w = (const float*)d_in[10];
  const float* m2b = (const float*)d_in[11];
  const float* m3w = (const float*)d_in[12];
  const float* m3b = (const float*)d_in[13];
  float* out = (float*)d_out;
  float* ws  = (float*)d_ws;
  const int B = in_sizes[0] / 32;

  hipLaunchKernelGGL(IDSSM_pre, dim3(5), dim3(256), 0, stream,
                     Wg, ag, p1w, p1b, p2w, p2b, m1w, m1b, m2w, m3w, ws);
  const int nblk = (B + 63) / 64;
  hipLaunchKernelGGL(IDSSM_main, dim3(nblk), dim3(256), 0, stream,
                     xs, stx, Wg, m2b, m3b, ws, out, B);
}